// Round 10
// baseline (1201.534 us; speedup 1.0000x reference)
//
#include <hip/hip_runtime.h>
#include <hip/hip_bf16.h>
#include <cstddef>
#include <math.h>

// ---------------------------------------------------------------------------
// Round 9: mgemm wave decomposition 4x(64x64) -> 2x(64x128) (same 128x128
// block tile, same grids, same 3-buffer counted-vmcnt schedule). Halves the
// LDS fragment re-reads per MFMA (identified LDS-BW bound: 8KB/16 MFMA ->
// 12KB/32 MFMA per wave-K-step). Blocks are 128 threads, vmcnt(8).
// Everything else identical to round 8 (best: 1068 us).
// ---------------------------------------------------------------------------

constexpr int kB   = 16;
constexpr int kCin = 768;
constexpr int kHW  = 400;
constexpr int kWpx = 20;
constexpr int kHpx = 20;
constexpr int kD   = 512;
constexpr int kLen = 800;
constexpr int kDff = 1024;
constexpr int kNL  = 6;
constexpr float kEps = 1e-5f;

typedef __attribute__((ext_vector_type(8))) short s8v;
typedef __attribute__((ext_vector_type(4))) short s4v;
typedef __attribute__((ext_vector_type(4))) float f4v;

__device__ __forceinline__ int swzk(int row, int k) {
  return (k & ~31) | ((((k >> 3) + (row >> 1)) & 3) << 3) | (k & 7);
}

__device__ __forceinline__ unsigned short f2b(float f) {
  union { __hip_bfloat16 h; unsigned short u; } cv;
  cv.h = __float2bfloat16(f);
  return cv.u;
}

__device__ __forceinline__ float b2f(unsigned short u) {
  return __uint_as_float(((unsigned)u) << 16);
}

__device__ __forceinline__ void gll(const unsigned short* g, unsigned short* l) {
  __builtin_amdgcn_global_load_lds(
      (const __attribute__((address_space(1))) unsigned int*)g,
      (__attribute__((address_space(3))) unsigned int*)l, 16, 0, 0);
}

// ------------------------------ block reduce -------------------------------
__device__ __forceinline__ void breduce2(float& s, float& s2, float* sh) {
#pragma unroll
  for (int o = 32; o > 0; o >>= 1) {
    s  += __shfl_down(s, o);
    s2 += __shfl_down(s2, o);
  }
  const int wid = threadIdx.x >> 6, lane = threadIdx.x & 63;
  if (lane == 0) { sh[wid] = s; sh[4 + wid] = s2; }
  __syncthreads();
  if (threadIdx.x == 0) {
    sh[0] = sh[0] + sh[1] + sh[2] + sh[3];
    sh[4] = sh[4] + sh[5] + sh[6] + sh[7];
  }
  __syncthreads();
  s = sh[0]; s2 = sh[4];
}

// ------------------------------- MFMA GEMM ---------------------------------
// 128x128 block tile, 2 waves x (64 rows x 128 cols), BK=32, 3-buffer
// 2-deep prefetch, counted vmcnt(8), raw s_barrier, setprio around MFMA.
// Wave 0 stages A (8 gll), wave 1 stages B (8 gll).
// EPI 1: bf16 Cb[row*ldc + swzk] = relu(acc+bias)            (ffn hidden)
// EPI 2: bf16 Cb[row*512+col] = acc+bias + res(srcb swz)     (pre-LN y)
// EPI 3: bf16 Cb[((row/400)*Nreal+col)*400 + row%400] = acc+bias (conv out)
// EPI 4: col<512 -> bf16 Cb[row*512+col] (value, plain);
//        col in [512,704) -> bf16 Cb2[row*192+c] = acc + aux[(row%800)*192+c]
// EPI 5: posWc writer: Cf[((col>>8)*800 + row)*192 + (col&255)] = acc+bias
// EPI 6: plain bf16 Cb[row*512+col]; rows >= 6400 use resb/aux as W/bias
template<int EPI>
__global__ __launch_bounds__(128, 2)
void mgemm(const unsigned short* __restrict__ Abf,
           const unsigned short* __restrict__ Bw,
           const float* __restrict__ bias,
           const unsigned short* __restrict__ resb,
           float* __restrict__ Cf, unsigned short* __restrict__ Cb2,
           const float* __restrict__ aux,
           unsigned short* __restrict__ Cb,
           int K, int ldc, int Nreal)
{
  __shared__ unsigned short LDS[3][8192];   // [buf][A 0..4095 | B 4096..8191]
  const int tid = threadIdx.x;
  const int w = tid >> 6, l = tid & 63;

  // bijective XCD-aware swizzle (m204)
  const int gx = gridDim.x;
  const int nwg = gx * gridDim.y;
  const int bid = blockIdx.y * gx + blockIdx.x;
  const int q = nwg >> 3, r = nwg & 7;
  const int xcd = bid & 7, idx = bid >> 3;
  const int wgid = (xcd < r ? xcd * (q + 1) : r * (q + 1) + (xcd - r) * q) + idx;
  const int m0 = (wgid / gx) * 128;
  const int n0 = (wgid % gx) * 128;

  if (EPI == 6 && m0 >= 6400) { Bw = resb; bias = aux; }

  f4v acc[4][8] = {};

  // staging: wave 0 -> A half, wave 1 -> B half (8 x 1KB chunks each)
  const unsigned short* gsrc =
      (w == 0 ? Abf + (size_t)(m0 + (l >> 2)) * K
              : Bw  + (size_t)(n0 + (l >> 2)) * K) + (l & 3) * 8;
  const int wsel = w ? 4096 : 0;

  auto STAGE = [&](int ko, int bi) {
#pragma unroll
    for (int c = 0; c < 8; c++)
      gll(gsrc + (size_t)(c * 16) * K + ko, &LDS[bi][wsel + c * 512]);
  };

  // fragment LDS offsets (shorts), swizzle folded in
  int aoff[4], boff[8];
#pragma unroll
  for (int i = 0; i < 4; i++) {
    const int ra = w * 64 + i * 16 + (l & 15);
    aoff[i] = ra * 32 + ((((l >> 4) + (ra >> 1)) & 3) << 3);
  }
#pragma unroll
  for (int j = 0; j < 8; j++) {
    const int rb = j * 16 + (l & 15);
    boff[j] = 4096 + rb * 32 + ((((l >> 4) + (rb >> 1)) & 3) << 3);
  }

  const int NT = K >> 5;
  STAGE(0, 0);
  STAGE(32, 1);

  int cur = 0;
  int bpre = 2;
  int kpre = 64;
  for (int t = 0; t < NT; ++t) {
    if (t + 1 < NT) asm volatile("s_waitcnt vmcnt(8)" ::: "memory");
    else            asm volatile("s_waitcnt vmcnt(0)" ::: "memory");
    __builtin_amdgcn_s_barrier();
    __builtin_amdgcn_sched_barrier(0);
    if (t + 2 < NT) STAGE(kpre, bpre);
    s8v af[4], bf8[8];
#pragma unroll
    for (int i = 0; i < 4; i++) af[i] = *(const s8v*)&LDS[cur][aoff[i]];
#pragma unroll
    for (int j = 0; j < 8; j++) bf8[j] = *(const s8v*)&LDS[cur][boff[j]];
    __builtin_amdgcn_s_setprio(1);
#pragma unroll
    for (int i = 0; i < 4; i++)
#pragma unroll
      for (int j = 0; j < 8; j++)
        acc[i][j] = __builtin_amdgcn_mfma_f32_16x16x32_bf16(af[i], bf8[j], acc[i][j], 0, 0, 0);
    __builtin_amdgcn_s_setprio(0);
    kpre += 32;
    bpre = (bpre == 2) ? 0 : bpre + 1;
    cur  = (cur == 2) ? 0 : cur + 1;
  }

  // C/D layout: col=lane&15, row=(lane>>4)*4+reg
  const int rowb = m0 + w * 64 + (l >> 4) * 4;
#pragma unroll
  for (int i = 0; i < 4; i++) {
#pragma unroll
    for (int j = 0; j < 8; j++) {
      const int col = n0 + j * 16 + (l & 15);
      float bv;
      if (EPI == 4) bv = (col < kD) ? bias[col] : 0.0f;
      else          bv = bias[col];
#pragma unroll
      for (int r2 = 0; r2 < 4; r2++) {
        const int row = rowb + i * 16 + r2;
        float v = acc[i][j][r2] + bv;
        if (EPI == 1) {
          Cb[(size_t)row * ldc + swzk(row, col)] = f2b(fmaxf(v, 0.0f));
        } else if (EPI == 2) {
          v += b2f(resb[(size_t)row * kD + swzk(row, col)]);
          Cb[(size_t)row * kD + col] = f2b(v);
        } else if (EPI == 3) {
          const int bb = row / kHW, p = row % kHW;
          Cb[((size_t)bb * Nreal + col) * kHW + p] = f2b(v);
        } else if (EPI == 4) {
          if (col < kD) {
            Cb[(size_t)row * kD + col] = f2b(v);
          } else {
            const int c = col - kD;
            if (c < 192)
              Cb2[(size_t)row * 192 + c] = f2b(v + aux[(size_t)(row % kLen) * 192 + c]);
          }
        } else if (EPI == 5) {
          if (row < kLen) {
            const int ll = col >> 8, c = col & 255;
            if (c < 192)
              Cf[(((size_t)ll * kLen) + row) * 192 + c] = v;
          }
        } else {  // EPI == 6
          Cb[(size_t)row * kD + col] = f2b(v);
        }
      }
    }
  }
}

// -------------------------- weight conversions -----------------------------
__device__ __forceinline__ void cvt8t(const float* __restrict__ W,
                                      unsigned short* __restrict__ out,
                                      int K, int N, int g)
{
  const int n = g % N;
  const int k = (g / N) * 8;
  s8v p;
#pragma unroll
  for (int j = 0; j < 8; j++) p[j] = (short)f2b(W[(size_t)(k + j) * N + n]);
  const int base = n * K + (k & ~31) + ((((k >> 3) + (n >> 1)) & 3) << 3);
  *(s8v*)&out[base] = p;
}

// ALL 6 layers' weights in one dispatch: 6 x 212,992 items, 4992 blocks.
__global__ __launch_bounds__(256)
void cvt_all_k(const float* __restrict__ vp_w, const float* __restrict__ op_w,
               const float* __restrict__ off_w, const float* __restrict__ aw_w,
               const float* __restrict__ f1w_a, const float* __restrict__ f2w_a,
               unsigned short* __restrict__ wall)
{
  const int lyr = blockIdx.x / 832;
  int g = (blockIdx.x % 832) * 256 + threadIdx.x;
  unsigned short* wl = wall + (size_t)lyr * 1703936;
  if (g < 32768) { cvt8t(vp_w + (size_t)lyr * kD * kD, wl, 512, 512, g); return; }
  g -= 32768;
  if (g < 16384) {                       // [ow|aww] -> wcomb rows 512..767
    const int n = g & 255;
    const int k = (g >> 8) * 8;
    const float* ow  = off_w + (size_t)lyr * kD * 128;
    const float* aww = aw_w  + (size_t)lyr * kD * 64;
    s8v p;
#pragma unroll
    for (int j = 0; j < 8; j++) {
      float v = 0.0f;
      if (n < 128)      v = ow[(size_t)(k + j) * 128 + n];
      else if (n < 192) v = aww[(size_t)(k + j) * 64 + (n - 128)];
      p[j] = (short)f2b(v);
    }
    const int row = 512 + n;
    const int base = row * 512 + (k & ~31) + ((((k >> 3) + (row >> 1)) & 3) << 3);
    *(s8v*)&wl[base] = p;
    return;
  }
  g -= 16384;
  if (g < 32768) { cvt8t(op_w + (size_t)lyr * kD * kD, wl + 393216, 512, 512, g); return; }
  g -= 32768;
  if (g < 65536) { cvt8t(f1w_a + (size_t)lyr * kD * kDff, wl + 655360, 512, 1024, g); return; }
  g -= 65536;
  cvt8t(f2w_a + (size_t)lyr * kDff * kD, wl + 1179648, 1024, 512, g);
}

// pre: positional features bf16 swz [896][512] + all-layer [ow|aww] + biases
__global__ __launch_bounds__(256)
void pre_k(const float* __restrict__ level_embed,
           const float* __restrict__ off_w, const float* __restrict__ aw_w,
           const float* __restrict__ off_b, const float* __restrict__ aw_b,
           unsigned short* __restrict__ posfb,
           unsigned short* __restrict__ woaw_all, float* __restrict__ biasall)
{
  int g = blockIdx.x * 256 + threadIdx.x;
  if (g < 57344) {                            // posfb: 896*64
    const int d0 = (g & 63) * 8;
    const int t  = g >> 6;
    s8v o;
    if (t >= kLen) {
#pragma unroll
      for (int j = 0; j < 8; j++) o[j] = 0;
    } else {
      const int lvl = t / kHW;
      const int tt = t % kHW;
      const int yy = tt / kWpx, xx = tt % kWpx;
#pragma unroll
      for (int j = 0; j < 8; j++) {
        const int d = d0 + j;
        const int dd = d & 255;
        const float e = (d < 256) ? ((float)(yy + 1) * (6.283185307179586f / kHpx))
                                  : ((float)(xx + 1) * (6.283185307179586f / kWpx));
        const float dimt = powf(10000.0f, (float)(dd >> 1) / 128.0f);
        const float pp = e / dimt;
        const float val = (dd & 1) ? cosf(pp) : sinf(pp);
        o[j] = (short)f2b(val + level_embed[lvl * kD + d]);
      }
    }
    *(s8v*)&posfb[(size_t)t * kD + swzk(t, d0)] = o;
    return;
  }
  g -= 57344;
  if (g < 98304) {                            // woaw_all
    const int l = g >> 14;
    const int gg = g & 16383;
    const int n = gg & 255;
    const int k = (gg >> 8) * 8;
    const float* ow = off_w + (size_t)l * kD * 128;
    const float* aww = aw_w + (size_t)l * kD * 64;
    s8v p;
#pragma unroll
    for (int j = 0; j < 8; j++) {
      float v = 0.0f;
      if (n < 128)      v = ow[(size_t)(k + j) * 128 + n];
      else if (n < 192) v = aww[(size_t)(k + j) * 64 + (n - 128)];
      p[j] = (short)f2b(v);
    }
    const int row = l * 256 + n;
    const int base = row * 512 + (k & ~31) + ((((k >> 3) + (row >> 1)) & 3) << 3);
    *(s8v*)&woaw_all[base] = p;
    return;
  }
  g -= 98304;                                 // biasall < 1536
  if (g < 1536) {
    const int l = g >> 8, c = g & 255;
    float v = 0.0f;
    if (c < 128)      v = off_b[l * 128 + c];
    else if (c < 192) v = aw_b[l * 64 + (c - 128)];
    biasall[l * 256 + c] = v;
  }
}

// input transpose (both mods) + both conv weight converts, one dispatch
__global__ void tincvt_k(const float* __restrict__ inv, const float* __restrict__ ini,
                         const float* __restrict__ W0, const float* __restrict__ W1,
                         unsigned short* __restrict__ out, unsigned short* __restrict__ wcs)
{
  __shared__ float t[16][17];
  const int bid = blockIdx.x;
  if (bid < 38400) {                      // transpose: 48 x 25 x 32
    const int z = bid / 1200;             // mod*16+b
    const int rem = bid % 1200;
    const int c0 = (rem % 48) * 16, p0 = (rem / 48) * 16;
    const int mod = z >> 4, b = z & 15;
    const float* in = (mod ? ini : inv) + (size_t)b * kCin * kHW;
    const int tx = threadIdx.x & 15, ty = threadIdx.x >> 4;
    t[ty][tx] = in[((size_t)(c0 + ty)) * kHW + p0 + tx];
    __syncthreads();
    const int row = z * kHW + p0 + ty;
    const int c = c0 + tx;
    out[(size_t)row * kCin + swzk(row, c)] = f2b(t[tx][ty]);
    return;
  }
  int gid = (bid - 38400) * 256 + threadIdx.x;   // < 2*512*96
  const float* W = W0;
  unsigned short* o = wcs;
  if (gid >= 49152) { gid -= 49152; W = W1; o = wcs + 393216; }
  const int n = gid / 96;
  const int k = (gid % 96) * 8;
  s8v p;
#pragma unroll
  for (int j = 0; j < 8; j++) p[j] = (short)f2b(W[(size_t)n * kCin + k + j]);
  const int base = n * kCin + (k & ~31) + ((((k >> 3) + (n >> 1)) & 3) << 3);
  *(s8v*)&o[base] = p;
}

// ------------------ GroupNorm (token-major, bf16 input) ---------------------
__global__ __launch_bounds__(256)
void gn_stats_tok_k(const unsigned short* __restrict__ x, float* __restrict__ stats)
{
  __shared__ float sh[8];
  const int mb = blockIdx.x >> 5;   // mod*16+b
  const int g = blockIdx.x & 31;
  const unsigned short* xb = x + (size_t)mb * kHW * kD + g * 16;
  float s = 0.f, s2 = 0.f;
  for (int i = threadIdx.x; i < 800; i += 256) {
    const int p = i >> 1, half = i & 1;
    const s8v u = *(const s8v*)&xb[(size_t)p * kD + half * 8];
#pragma unroll
    for (int j = 0; j < 8; j++) {
      const float v = b2f((unsigned short)u[j]);
      s += v; s2 += v * v;
    }
  }
  breduce2(s, s2, sh);
  if (threadIdx.x == 0) {
    const float mean = s / (kHW * 16.0f);
    const float var  = s2 / (kHW * 16.0f) - mean * mean;
    stats[blockIdx.x * 2]     = mean;
    stats[blockIdx.x * 2 + 1] = rsqrtf(var + kEps);
  }
}

__global__ void gn_norm_tok_k(const unsigned short* __restrict__ x,
                              unsigned short* __restrict__ srcb,
                              const float* __restrict__ stats,
                              const float* __restrict__ gv, const float* __restrict__ bev,
                              const float* __restrict__ gi, const float* __restrict__ bei)
{
  const int gid = blockIdx.x * 256 + threadIdx.x;   // < 12800*64
  const int d0 = (gid & 63) * 8;
  const int rl = gid >> 6;                          // (mod*16+b)*400+p
  const int mb = rl / kHW;
  const int p  = rl - mb * kHW;
  const int mod = mb >> 4, b = mb & 15;
  const int g = d0 >> 4;
  const float mean = stats[(mb * 32 + g) * 2];
  const float rstd = stats[(mb * 32 + g) * 2 + 1];
  const float* gam = mod ? gi : gv;
  const float* bet = mod ? bei : bev;
  const s8v u = *(const s8v*)&x[(size_t)rl * kD + d0];
  const int row = b * kLen + mod * kHW + p;
  s8v o;
#pragma unroll
  for (int j = 0; j < 8; j++)
    o[j] = (short)f2b((b2f((unsigned short)u[j]) - mean) * rstd * gam[d0 + j] + bet[d0 + j]);
  *(s8v*)&srcb[(size_t)row * kD + swzk(row, d0)] = o;
}

// ---------------- GroupNorm (chan-major, bf16 scratch input) ----------------
__global__ __launch_bounds__(256)
void gn_stats_ch_k(const unsigned short* __restrict__ x, float* __restrict__ stats)
{
  __shared__ float sh[8];
  const int b = blockIdx.x >> 5;
  const int g = blockIdx.x & 31;
  const unsigned short* xb = x + (size_t)b * kCin * kHW + (size_t)g * 24 * kHW;
  float s = 0.f, s2 = 0.f;
  for (int i = threadIdx.x; i < 1200; i += 256) {
    const s8v u = *(const s8v*)&xb[(size_t)i * 8];
#pragma unroll
    for (int j = 0; j < 8; j++) {
      const float v = b2f((unsigned short)u[j]);
      s += v; s2 += v * v;
    }
  }
  breduce2(s, s2, sh);
  if (threadIdx.x == 0) {
    const float mean = s / (24.0f * kHW);
    const float var  = s2 / (24.0f * kHW) - mean * mean;
    stats[blockIdx.x * 2]     = mean;
    stats[blockIdx.x * 2 + 1] = rsqrtf(var + kEps);
  }
}

__global__ void gn_norm_ch_k(const unsigned short* __restrict__ x, float* __restrict__ out,
                             const float* __restrict__ stats,
                             const float* __restrict__ gam, const float* __restrict__ bet)
{
  const int gid = blockIdx.x * 256 + threadIdx.x;   // < 16*768*400/8
  const int idx8 = gid * 8;
  const int rest = idx8 / kHW;
  const int c = rest % kCin;
  const int b = rest / kCin;
  const int g = c / 24;
  const float mean = stats[(b * 32 + g) * 2];
  const float rstd = stats[(b * 32 + g) * 2 + 1];
  const float gg = gam[c], bb = bet[c];
  const s8v u = *(const s8v*)&x[idx8];
  float4 o0, o1;
  o0.x = (b2f((unsigned short)u[0]) - mean) * rstd * gg + bb;
  o0.y = (b2f((unsigned short)u[1]) - mean) * rstd * gg + bb;
  o0.z = (b2f((unsigned short)u[2]) - mean) * rstd * gg + bb;
  o0.w = (b2f((unsigned short)u[3]) - mean) * rstd * gg + bb;
  o1.x = (b2f((unsigned short)u[4]) - mean) * rstd * gg + bb;
  o1.y = (b2f((unsigned short)u[5]) - mean) * rstd * gg + bb;
  o1.z = (b2f((unsigned short)u[6]) - mean) * rstd * gg + bb;
  o1.w = (b2f((unsigned short)u[7]) - mean) * rstd * gg + bb;
  *(float4*)(out + idx8)     = o0;
  *(float4*)(out + idx8 + 4) = o1;
}

// ------------- modality-specific LayerNorm (wave/row, bf16 in) --------------
__global__ __launch_bounds__(256)
void ln4_k(const unsigned short* __restrict__ x, unsigned short* __restrict__ outb,
           const float* __restrict__ gamma, const float* __restrict__ beta)
{
  const int row = blockIdx.x * 4 + (threadIdx.x >> 6);
  const int l = threadIdx.x & 63;
  const int mod = ((row % kLen) < kHW) ? 0 : 1;
  const s8v u = *(const s8v*)&x[(size_t)row * kD + l * 8];
  float v[8];
#pragma unroll
  for (int j = 0; j < 8; j++) v[j] = b2f((unsigned short)u[j]);
  float s = 0.f, s2 = 0.f;
#pragma unroll
  for (int j = 0; j < 8; j++) { s += v[j]; s2 += v[j] * v[j]; }
#pragma unroll
  for (int o = 32; o > 0; o >>= 1) {
    s  += __shfl_xor(s, o);
    s2 += __shfl_xor(s2, o);
  }
  const float mean = s * (1.0f / kD);
  const float var  = s2 * (1.0f / kD) - mean * mean;
  const float rstd = rsqrtf(var + kEps);
  const float* g  = gamma + mod * kD + l * 8;
  const float* be = beta  + mod * kD + l * 8;
  s8v o8;
#pragma unroll
  for (int j = 0; j < 8; j++)
    o8[j] = (short)f2b((v[j] - mean) * rstd * g[j] + be[j]);
  *(s8v*)&outb[(size_t)row * kD + swzk(row, l * 8)] = o8;
}

// ------------------- deformable sampling (bf16 value/offaw) -----------------
__global__ __launch_bounds__(256)
void sample_k(const unsigned short* __restrict__ value,
              const unsigned short* __restrict__ offaw,
              unsigned short* __restrict__ out)
{
  __shared__ float wls[2][64][8];   // [tok][combo][w0,i0,...,w3,i3]
  const int tid = threadIdx.x;
  const int tok = tid >> 7;
  const int wt  = tid & 127;
  const int token = blockIdx.x * 2 + tok;       // < 12800
  const int b = token / kLen;
  const int t = token % kLen;
  const int tt = t % kHW;

  if (wt < 64) {
    const int h = wt >> 3, lp = wt & 7, lvl = lp >> 2, p = lp & 3;
    const unsigned short* oa = offaw + (size_t)token * 192;
    const float lg = b2f(oa[128 + h * 8 + lp]);
    float mx = lg;
#pragma unroll
    for (int msk = 1; msk < 8; msk <<= 1) mx = fmaxf(mx, __shfl_xor(mx, msk));
    const float ex = __expf(lg - mx);
    float ssum = ex;
#pragma unroll
    for (int msk = 1; msk < 8; msk <<= 1) ssum += __shfl_xor(ssum, msk);
    const float aw = ex / ssum;

    const float x = (float)(tt % kWpx) + b2f(oa[h * 16 + lvl * 8 + p * 2]);
    const float y = (float)(tt / kWpx) + b2f(oa[h * 16 + lvl * 8 + p * 2 + 1]);
    const float x0f = floorf(x), y0f = floorf(y);
    const float wx = x - x0f, wy = y - y0f;
    const int x0 = (int)x0f, y0 = (int)y0f;
    const int rowbase = b * kLen + lvl * kHW;
#pragma unroll
    for (int dy = 0; dy < 2; dy++) {
#pragma unroll
      for (int dx = 0; dx < 2; dx++) {
        const int ix = x0 + dx, iy = y0 + dy;
        const bool valid = (ix >= 0) & (ix < kWpx) & (iy >= 0) & (iy < kHpx);
        const float cw = (dx ? wx : 1.0f - wx) * (dy ? wy : 1.0f - wy);
        const float w = valid ? aw * cw : 0.0f;
        const int ixc = min(max(ix, 0), kWpx - 1);
        const int iyc = min(max(iy, 0), kHpx - 1);
        const int r = rowbase + iyc * kWpx + ixc;
        const int cn = dy * 2 + dx;
        wls[tok][wt][cn * 2]     = w;
        wls[tok][wt][cn * 2 + 1] = __int_as_float(r);
      }
    }
  }
  __syncthreads();

  const int c0 = wt * 4;
  const int h = wt >> 4;
  float acc0 = 0.f, acc1 = 0.f, acc2 = 0.f, acc3 = 0.f;
  const unsigned short* vb = value + c0;
#pragma unroll
  for (int pp = 0; pp < 8; pp++) {
    const float* wl = wls[tok][h * 8 + pp];
#pragma unroll
    for (int cn = 0; cn < 4; cn++) {
      const float w = wl[cn * 2];
      const int r = __float_as_int(wl[cn * 2 + 1]);
      const s4v q = *(const s4v*)(vb + (size_t)r * kD);
      acc0 += w * b2f((unsigned short)q[0]);
      acc1 += w * b2f((unsigned short)q[1]);
      acc2 += w * b2f((unsigned short)q[2]);
      acc3 += w * b2f((unsigned short)q[3]);
    }
  }
  const int sk = swzk(token, c0);
  s4v o;
  o[0] = (short)f2b(acc0); o[1] = (short)f2b(acc1);
  o[2] = (short)f2b(acc2); o[3] = (short)f2b(acc3);
  *(s4v*)&out[(size_t)token * kD + sk] = o;
}

// -------- token-sum (srcb halves -> tokb swz) + as_w convert, fused ---------
__global__ void sumcvt_k(const unsigned short* __restrict__ srcb,
                         unsigned short* __restrict__ tokb,
                         const float* __restrict__ asw,
                         unsigned short* __restrict__ wcs)
{
  const int bid = blockIdx.x;
  if (bid < 1600) {                              // sumtok: 16*400*64 items
    const int gid = bid * 256 + threadIdx.x;
    const int d0 = (gid & 63) * 8;
    const int rest = gid >> 6;
    const int b = rest / kHW, p = rest % kHW;
    const int r1 = b * kLen + p;
    const int r2 = r1 + kHW;
    const int ro = b * kHW + p;
    const s8v u1 = *(const s8v*)&srcb[(size_t)r1 * kD + swzk(r1, d0)];
    const s8v u2 = *(const s8v*)&srcb[(size_t)r2 * kD + swzk(r2, d0)];
    s8v o;
#pragma unroll
    for (int j = 0; j < 8; j++)
      o[j] = (short)f2b(b2f((unsigned short)u1[j]) + b2f((unsigned short)u2[j]));
    *(s8v*)&tokb[(size_t)ro * kD + swzk(ro, d0)] = o;
    return;
  }
  const int gid = (bid - 1600) * 256 + threadIdx.x;   // < 768*64 (N=768, K=512)
  const int n = gid / 64;
  const int k = (gid % 64) * 8;
  s8v p;
#pragma unroll
  for (int j = 0; j < 8; j++) p[j] = (short)f2b(asw[(size_t)n * kD + k + j]);
  const int base = n * kD + (k & ~31) + ((((k >> 3) + (n >> 1)) & 3) << 3);
  *(s8v*)&wcs[base] = p;
}

// ------------------------------- launcher -----------------------------------
extern "C" void kernel_launch(void* const* d_in, const int* in_sizes, int n_in,
                              void* d_out, int out_size, void* d_ws, size_t ws_size,
                              hipStream_t stream)
{
  const float* input_v     = (const float*)d_in[0];
  const float* input_i     = (const float*)d_in[1];
  const float* av_w        = (const float*)d_in[2];
  const float* av_b        = (const float*)d_in[3];
  const float* av_g        = (const float*)d_in[4];
  const float* av_be       = (const float*)d_in[5];
  const float* ai_w        = (const float*)d_in[6];
  const float* ai_b        = (const float*)d_in[7];
  const float* ai_g        = (const float*)d_in[8];
  const float* ai_be       = (const float*)d_in[9];
  const float* level_embed = (const float*)d_in[10];
  const float* off_w       = (const float*)d_in[11];
  const float* off_b       = (const float*)d_in[12];
  const float* aw_w        = (const float*)d_in[13];
  const float* aw_b        = (const float*)d_in[14];
  const float* vp_w        = (const float*)d_in[15];
  const float* vp_b        = (const float*)d_in[16];
  const float* op_w        = (const float*)d_in[17];
  const float* op_b        = (const float*)d_in[18];
  const float* ln1_g       = (const float*)d_in[19];
  const float* ln1_b       = (const float*)d_in[20];
  const float* ffn1_w      = (const float*)d_in[21];
  const float* ffn1_b      = (const float*)d_in[22];
  const float* ffn2_w      = (const float*)d_in[23];
  const float* ffn2_b      = (const float*)d_in[24];
  const float* ln2_g       = (const float*)d_in[25];
  const float* ln2_b       = (const float*)d_in[26];
  const float* as_w        = (const float*)d_in[27];
  const float* as_b        = (const float*)d_in[28];
  const float* as_g        = (const float*)d_in[29];
  const float* as_be       = (const float*)d_in[30];

  // ------- workspace layout -------
  unsigned short* offawb = (unsigned short*)d_ws;               // 2,457,600 sh
  float* posWc   = (float*)(offawb + 2457600);                  //   921,600 f
  float* biasall = posWc   + (size_t)921600;                    //     1,536 f
  float* stats   = biasall + (size_t)1536;                      //     2,048 f
  unsigned short* srcb     = (unsigned short*)(stats + 2048);   //  6,553,600 sh
  unsigned short* bufA     = srcb     + (size_t)6553600;        // 13,107,200 sh
  unsigned short* bufB     = bufA     + (size_t)13107200;       //  6,553,600 sh
  unsigned short* wall     = bufB     + (size_t)6553600;        // 10,223,616 sh
  unsigned short* wcs      = wall     + (size_t)10223616;       //    786,432 sh
  unsigned short* woaw_all = wcs      + (size_t)786432;         //    786,432 sh
  unsigned short* posfb    = woaw_all + (size_t)786432;         //    458,752 sh
  unsigned short* wallb = wall;   // bf16 conv scratch (aliases weight arena)

  const int M = kB * kLen;   // 12800

  // ---- pre: posfb + woaw + biases (1 dispatch), then posWc GEMM ----
  pre_k<<<dim3(614), 256, 0, stream>>>(level_embed, off_w, aw_w, off_b, aw_b,
                                       posfb, woaw_all, biasall);
  mgemm<5><<<dim3(12, 7), 128, 0, stream>>>(
      posfb, woaw_all, biasall, nullptr, posWc, nullptr, nullptr, nullptr,
      512, 0, 0);

  // ---- input convs (both modalities, one GEMM) + GN -> srcb ----
  tincvt_k<<<dim3(38784), 256, 0, stream>>>(input_v, input_i, av_w, ai_w,
                                            bufA, wcs);
  mgemm<6><<<dim3(4, 100), 128, 0, stream>>>(
      bufA, wcs, av_b, wcs + 393216, nullptr, nullptr, ai_b, bufB, 768, 512, 0);
  gn_stats_tok_k<<<dim3(1024), 256, 0, stream>>>(bufB, stats);
  gn_norm_tok_k<<<dim3(3200), 256, 0, stream>>>(
      bufB, srcb, stats, av_g, av_be, ai_g, ai_be);

  // ---- all layer weights -> wall (one dispatch) ----
  cvt_all_k<<<dim3(4992), 256, 0, stream>>>(vp_w, op_w, off_w, aw_w,
                                            ffn1_w, ffn2_w, wall);

  for (int l = 0; l < kNL; l++) {
    unsigned short* wcomb = wall + (size_t)l * 1703936;
    unsigned short* wop   = wcomb + 393216;
    unsigned short* wf1   = wcomb + 655360;
    unsigned short* wf2   = wcomb + 1179648;
    const float* vbl  = vp_b   + (size_t)l * kD;
    const float* opbl = op_b   + (size_t)l * kD;
    const float* l1g  = ln1_g  + (size_t)l * 2 * kD;
    const float* l1b  = ln1_b  + (size_t)l * 2 * kD;
    const float* f1b  = ffn1_b + (size_t)l * kDff;
    const float* f2b_ = ffn2_b + (size_t)l * kD;
    const float* l2g  = ln2_g  + (size_t)l * 2 * kD;
    const float* l2b  = ln2_b  + (size_t)l * 2 * kD;

    // fused: value bf16 (bufA) | offaw bf16 (+posWc)
    mgemm<4><<<dim3(6, 100), 128, 0, stream>>>(
        srcb, wcomb, vbl, nullptr, nullptr, offawb, posWc + (size_t)l * 153600,
        bufA, 512, 0, 0);

    // sampling -> bufB (bf16 swz)
    sample_k<<<dim3(M / 2), 256, 0, stream>>>(bufA, offawb, bufB);

    // y = srcb + sampled @ op + opb -> bufA (bf16 plain)
    mgemm<2><<<dim3(4, 100), 128, 0, stream>>>(
        bufB, wop, opbl, srcb, nullptr, nullptr, nullptr, bufA, 512, 512, 0);

    // srcb = LN_spec(y)
    ln4_k<<<dim3(M / 4), 256, 0, stream>>>(bufA, srcb, l1g, l1b);

    // FFN full-M: hidden -> bufA (swz, relu); y -> bufB (plain)
    mgemm<1><<<dim3(8, 100), 128, 0, stream>>>(
        srcb, wf1, f1b, nullptr, nullptr, nullptr, nullptr, bufA, 512, 1024, 0);
    mgemm<2><<<dim3(4, 100), 128, 0, stream>>>(
        bufA, wf2, f2b_, srcb, nullptr, nullptr, nullptr, bufB, 1024, 512, 0);

    // srcb = LN_spec(y)
    ln4_k<<<dim3(M / 4), 256, 0, stream>>>(bufB, srcb, l2g, l2b);
  }

  // ---- out = GN(conv1x1(src_v + src_i)); bf16 scratch in wallb ----
  sumcvt_k<<<dim3(1792), 256, 0, stream>>>(srcb, bufA, as_w, wcs);
  mgemm<3><<<dim3(6, 50), 128, 0, stream>>>(
      bufA, wcs, as_b, nullptr, nullptr, nullptr, nullptr, wallb, 512, 0, 768);
  gn_stats_ch_k<<<dim3(kB * 32), 256, 0, stream>>>(wallb, stats);
  gn_norm_ch_k<<<dim3(2400), 256, 0, stream>>>(
      wallb, (float*)d_out, stats, as_g, as_be);
}

// Round 11
// 1069.394 us; speedup vs baseline: 1.1236x; 1.1236x over previous
//
#include <hip/hip_runtime.h>
#include <hip/hip_bf16.h>
#include <cstddef>
#include <math.h>

// ---------------------------------------------------------------------------
// Round 10: REVERT to round-8 structure (measured best 1068 us). Round 9's
// 2-wave/128-thread mgemm collapsed occupancy (6% occ, 54us/dispatch) —
// same failure mode as round 7. Round-8 config: 128x128 tile, 4 waves x
// (64x64), 3-buffer 2-deep prefetch, counted vmcnt(4), raw s_barrier,
// setprio, XCD swizzle; bf16 activations everywhere; fused pre/post kernels.
// ---------------------------------------------------------------------------

constexpr int kB   = 16;
constexpr int kCin = 768;
constexpr int kHW  = 400;
constexpr int kWpx = 20;
constexpr int kHpx = 20;
constexpr int kD   = 512;
constexpr int kLen = 800;
constexpr int kDff = 1024;
constexpr int kNL  = 6;
constexpr float kEps = 1e-5f;

typedef __attribute__((ext_vector_type(8))) short s8v;
typedef __attribute__((ext_vector_type(4))) short s4v;
typedef __attribute__((ext_vector_type(4))) float f4v;

__device__ __forceinline__ int swzk(int row, int k) {
  return (k & ~31) | ((((k >> 3) + (row >> 1)) & 3) << 3) | (k & 7);
}

__device__ __forceinline__ unsigned short f2b(float f) {
  union { __hip_bfloat16 h; unsigned short u; } cv;
  cv.h = __float2bfloat16(f);
  return cv.u;
}

__device__ __forceinline__ float b2f(unsigned short u) {
  return __uint_as_float(((unsigned)u) << 16);
}

__device__ __forceinline__ void gll(const unsigned short* g, unsigned short* l) {
  __builtin_amdgcn_global_load_lds(
      (const __attribute__((address_space(1))) unsigned int*)g,
      (__attribute__((address_space(3))) unsigned int*)l, 16, 0, 0);
}

// ------------------------------ block reduce -------------------------------
__device__ __forceinline__ void breduce2(float& s, float& s2, float* sh) {
#pragma unroll
  for (int o = 32; o > 0; o >>= 1) {
    s  += __shfl_down(s, o);
    s2 += __shfl_down(s2, o);
  }
  const int wid = threadIdx.x >> 6, lane = threadIdx.x & 63;
  if (lane == 0) { sh[wid] = s; sh[4 + wid] = s2; }
  __syncthreads();
  if (threadIdx.x == 0) {
    sh[0] = sh[0] + sh[1] + sh[2] + sh[3];
    sh[4] = sh[4] + sh[5] + sh[6] + sh[7];
  }
  __syncthreads();
  s = sh[0]; s2 = sh[4];
}

// ------------------------------- MFMA GEMM ---------------------------------
// EPI 1: bf16 Cb[row*ldc + swzk] = relu(acc+bias)            (ffn hidden)
// EPI 2: bf16 Cb[row*512+col] = acc+bias + res(srcb swz)     (pre-LN y)
// EPI 3: bf16 Cb[((row/400)*Nreal+col)*400 + row%400] = acc+bias (conv out)
// EPI 4: col<512 -> bf16 Cb[row*512+col] (value, plain);
//        col in [512,704) -> bf16 Cb2[row*192+c] = acc + aux[(row%800)*192+c]
// EPI 5: posWc writer: Cf[((col>>8)*800 + row)*192 + (col&255)] = acc+bias
// EPI 6: plain bf16 Cb[row*512+col]; rows >= 6400 use resb/aux as W/bias
template<int EPI>
__global__ __launch_bounds__(256)
void mgemm(const unsigned short* __restrict__ Abf,
           const unsigned short* __restrict__ Bw,
           const float* __restrict__ bias,
           const unsigned short* __restrict__ resb,
           float* __restrict__ Cf, unsigned short* __restrict__ Cb2,
           const float* __restrict__ aux,
           unsigned short* __restrict__ Cb,
           int K, int ldc, int Nreal)
{
  __shared__ unsigned short As[3][4096];
  __shared__ unsigned short Bs[3][4096];
  const int tid = threadIdx.x;
  const int w = tid >> 6, l = tid & 63;

  // bijective XCD-aware swizzle (m204)
  const int gx = gridDim.x;
  const int nwg = gx * gridDim.y;
  const int bid = blockIdx.y * gx + blockIdx.x;
  const int q = nwg >> 3, r = nwg & 7;
  const int xcd = bid & 7, idx = bid >> 3;
  const int wgid = (xcd < r ? xcd * (q + 1) : r * (q + 1) + (xcd - r) * q) + idx;
  const int m0 = (wgid / gx) * 128;
  const int n0 = (wgid % gx) * 128;

  if (EPI == 6 && m0 >= 6400) { Bw = resb; bias = aux; }

  f4v acc[4][4] = {};

  const int srow = w * 32 + (l >> 2);
  const unsigned short* ga0 = Abf + (size_t)(m0 + srow) * K + (l & 3) * 8;
  const unsigned short* ga1 = ga0 + (size_t)16 * K;
  const unsigned short* gb0 = Bw + (size_t)(n0 + srow) * K + (l & 3) * 8;
  const unsigned short* gb1 = gb0 + (size_t)16 * K;
  const int lb0 = (w * 32) * 32;
  const int lb1 = (w * 32 + 16) * 32;

  int aoff[4], boff[4];
#pragma unroll
  for (int f = 0; f < 4; f++) {
    const int ra = (w >> 1) * 64 + f * 16 + (l & 15);
    aoff[f] = ra * 32 + ((((l >> 4) + (ra >> 1)) & 3) << 3);
    const int rb = (w & 1) * 64 + f * 16 + (l & 15);
    boff[f] = rb * 32 + ((((l >> 4) + (rb >> 1)) & 3) << 3);
  }

#define STAGEG(ko, bi) do { \
    gll(ga0 + (ko), &As[bi][lb0]); gll(ga1 + (ko), &As[bi][lb1]); \
    gll(gb0 + (ko), &Bs[bi][lb0]); gll(gb1 + (ko), &Bs[bi][lb1]); } while (0)

  const int NT = K >> 5;
  STAGEG(0, 0);
  STAGEG(32, 1);

  int cur = 0;
  int bpre = 2;
  int kpre = 64;
  for (int t = 0; t < NT; ++t) {
    if (t + 1 < NT) asm volatile("s_waitcnt vmcnt(4)" ::: "memory");
    else            asm volatile("s_waitcnt vmcnt(0)" ::: "memory");
    __builtin_amdgcn_s_barrier();
    __builtin_amdgcn_sched_barrier(0);
    if (t + 2 < NT) STAGEG(kpre, bpre);
    s8v af[4], bf4[4];
#pragma unroll
    for (int f = 0; f < 4; f++) {
      af[f]  = *(const s8v*)&As[cur][aoff[f]];
      bf4[f] = *(const s8v*)&Bs[cur][boff[f]];
    }
    __builtin_amdgcn_s_setprio(1);
#pragma unroll
    for (int i = 0; i < 4; i++)
#pragma unroll
      for (int j = 0; j < 4; j++)
        acc[i][j] = __builtin_amdgcn_mfma_f32_16x16x32_bf16(af[i], bf4[j], acc[i][j], 0, 0, 0);
    __builtin_amdgcn_s_setprio(0);
    kpre += 32;
    bpre = (bpre == 2) ? 0 : bpre + 1;
    cur  = (cur == 2) ? 0 : cur + 1;
  }
#undef STAGEG

  // C/D layout: col=lane&15, row=(lane>>4)*4+reg
  const int colb = n0 + (w & 1) * 64;
  const int rowb = m0 + (w >> 1) * 64 + (l >> 4) * 4;
#pragma unroll
  for (int i = 0; i < 4; i++) {
#pragma unroll
    for (int j = 0; j < 4; j++) {
      const int col = colb + j * 16 + (l & 15);
      float bv;
      if (EPI == 4) bv = (col < kD) ? bias[col] : 0.0f;
      else          bv = bias[col];
#pragma unroll
      for (int r2 = 0; r2 < 4; r2++) {
        const int row = rowb + i * 16 + r2;
        float v = acc[i][j][r2] + bv;
        if (EPI == 1) {
          Cb[(size_t)row * ldc + swzk(row, col)] = f2b(fmaxf(v, 0.0f));
        } else if (EPI == 2) {
          v += b2f(resb[(size_t)row * kD + swzk(row, col)]);
          Cb[(size_t)row * kD + col] = f2b(v);
        } else if (EPI == 3) {
          const int bb = row / kHW, p = row % kHW;
          Cb[((size_t)bb * Nreal + col) * kHW + p] = f2b(v);
        } else if (EPI == 4) {
          if (col < kD) {
            Cb[(size_t)row * kD + col] = f2b(v);
          } else {
            const int c = col - kD;
            if (c < 192)
              Cb2[(size_t)row * 192 + c] = f2b(v + aux[(size_t)(row % kLen) * 192 + c]);
          }
        } else if (EPI == 5) {
          if (row < kLen) {
            const int ll = col >> 8, c = col & 255;
            if (c < 192)
              Cf[(((size_t)ll * kLen) + row) * 192 + c] = v;
          }
        } else {  // EPI == 6
          Cb[(size_t)row * kD + col] = f2b(v);
        }
      }
    }
  }
}

// -------------------------- weight conversions -----------------------------
__device__ __forceinline__ void cvt8t(const float* __restrict__ W,
                                      unsigned short* __restrict__ out,
                                      int K, int N, int g)
{
  const int n = g % N;
  const int k = (g / N) * 8;
  s8v p;
#pragma unroll
  for (int j = 0; j < 8; j++) p[j] = (short)f2b(W[(size_t)(k + j) * N + n]);
  const int base = n * K + (k & ~31) + ((((k >> 3) + (n >> 1)) & 3) << 3);
  *(s8v*)&out[base] = p;
}

// ALL 6 layers' weights in one dispatch: 6 x 212,992 items, 4992 blocks.
__global__ __launch_bounds__(256)
void cvt_all_k(const float* __restrict__ vp_w, const float* __restrict__ op_w,
               const float* __restrict__ off_w, const float* __restrict__ aw_w,
               const float* __restrict__ f1w_a, const float* __restrict__ f2w_a,
               unsigned short* __restrict__ wall)
{
  const int lyr = blockIdx.x / 832;
  int g = (blockIdx.x % 832) * 256 + threadIdx.x;
  unsigned short* wl = wall + (size_t)lyr * 1703936;
  if (g < 32768) { cvt8t(vp_w + (size_t)lyr * kD * kD, wl, 512, 512, g); return; }
  g -= 32768;
  if (g < 16384) {                       // [ow|aww] -> wcomb rows 512..767
    const int n = g & 255;
    const int k = (g >> 8) * 8;
    const float* ow  = off_w + (size_t)lyr * kD * 128;
    const float* aww = aw_w  + (size_t)lyr * kD * 64;
    s8v p;
#pragma unroll
    for (int j = 0; j < 8; j++) {
      float v = 0.0f;
      if (n < 128)      v = ow[(size_t)(k + j) * 128 + n];
      else if (n < 192) v = aww[(size_t)(k + j) * 64 + (n - 128)];
      p[j] = (short)f2b(v);
    }
    const int row = 512 + n;
    const int base = row * 512 + (k & ~31) + ((((k >> 3) + (row >> 1)) & 3) << 3);
    *(s8v*)&wl[base] = p;
    return;
  }
  g -= 16384;
  if (g < 32768) { cvt8t(op_w + (size_t)lyr * kD * kD, wl + 393216, 512, 512, g); return; }
  g -= 32768;
  if (g < 65536) { cvt8t(f1w_a + (size_t)lyr * kD * kDff, wl + 655360, 512, 1024, g); return; }
  g -= 65536;
  cvt8t(f2w_a + (size_t)lyr * kDff * kD, wl + 1179648, 1024, 512, g);
}

// pre: positional features bf16 swz [896][512] + all-layer [ow|aww] + biases
__global__ __launch_bounds__(256)
void pre_k(const float* __restrict__ level_embed,
           const float* __restrict__ off_w, const float* __restrict__ aw_w,
           const float* __restrict__ off_b, const float* __restrict__ aw_b,
           unsigned short* __restrict__ posfb,
           unsigned short* __restrict__ woaw_all, float* __restrict__ biasall)
{
  int g = blockIdx.x * 256 + threadIdx.x;
  if (g < 57344) {                            // posfb: 896*64
    const int d0 = (g & 63) * 8;
    const int t  = g >> 6;
    s8v o;
    if (t >= kLen) {
#pragma unroll
      for (int j = 0; j < 8; j++) o[j] = 0;
    } else {
      const int lvl = t / kHW;
      const int tt = t % kHW;
      const int yy = tt / kWpx, xx = tt % kWpx;
#pragma unroll
      for (int j = 0; j < 8; j++) {
        const int d = d0 + j;
        const int dd = d & 255;
        const float e = (d < 256) ? ((float)(yy + 1) * (6.283185307179586f / kHpx))
                                  : ((float)(xx + 1) * (6.283185307179586f / kWpx));
        const float dimt = powf(10000.0f, (float)(dd >> 1) / 128.0f);
        const float pp = e / dimt;
        const float val = (dd & 1) ? cosf(pp) : sinf(pp);
        o[j] = (short)f2b(val + level_embed[lvl * kD + d]);
      }
    }
    *(s8v*)&posfb[(size_t)t * kD + swzk(t, d0)] = o;
    return;
  }
  g -= 57344;
  if (g < 98304) {                            // woaw_all
    const int l = g >> 14;
    const int gg = g & 16383;
    const int n = gg & 255;
    const int k = (gg >> 8) * 8;
    const float* ow = off_w + (size_t)l * kD * 128;
    const float* aww = aw_w + (size_t)l * kD * 64;
    s8v p;
#pragma unroll
    for (int j = 0; j < 8; j++) {
      float v = 0.0f;
      if (n < 128)      v = ow[(size_t)(k + j) * 128 + n];
      else if (n < 192) v = aww[(size_t)(k + j) * 64 + (n - 128)];
      p[j] = (short)f2b(v);
    }
    const int row = l * 256 + n;
    const int base = row * 512 + (k & ~31) + ((((k >> 3) + (row >> 1)) & 3) << 3);
    *(s8v*)&woaw_all[base] = p;
    return;
  }
  g -= 98304;                                 // biasall < 1536
  if (g < 1536) {
    const int l = g >> 8, c = g & 255;
    float v = 0.0f;
    if (c < 128)      v = off_b[l * 128 + c];
    else if (c < 192) v = aw_b[l * 64 + (c - 128)];
    biasall[l * 256 + c] = v;
  }
}

// input transpose (both mods) + both conv weight converts, one dispatch
__global__ void tincvt_k(const float* __restrict__ inv, const float* __restrict__ ini,
                         const float* __restrict__ W0, const float* __restrict__ W1,
                         unsigned short* __restrict__ out, unsigned short* __restrict__ wcs)
{
  __shared__ float t[16][17];
  const int bid = blockIdx.x;
  if (bid < 38400) {                      // transpose: 48 x 25 x 32
    const int z = bid / 1200;             // mod*16+b
    const int rem = bid % 1200;
    const int c0 = (rem % 48) * 16, p0 = (rem / 48) * 16;
    const int mod = z >> 4, b = z & 15;
    const float* in = (mod ? ini : inv) + (size_t)b * kCin * kHW;
    const int tx = threadIdx.x & 15, ty = threadIdx.x >> 4;
    t[ty][tx] = in[((size_t)(c0 + ty)) * kHW + p0 + tx];
    __syncthreads();
    const int row = z * kHW + p0 + ty;
    const int c = c0 + tx;
    out[(size_t)row * kCin + swzk(row, c)] = f2b(t[tx][ty]);
    return;
  }
  int gid = (bid - 38400) * 256 + threadIdx.x;   // < 2*512*96
  const float* W = W0;
  unsigned short* o = wcs;
  if (gid >= 49152) { gid -= 49152; W = W1; o = wcs + 393216; }
  const int n = gid / 96;
  const int k = (gid % 96) * 8;
  s8v p;
#pragma unroll
  for (int j = 0; j < 8; j++) p[j] = (short)f2b(W[(size_t)n * kCin + k + j]);
  const int base = n * kCin + (k & ~31) + ((((k >> 3) + (n >> 1)) & 3) << 3);
  *(s8v*)&o[base] = p;
}

// ------------------ GroupNorm (token-major, bf16 input) ---------------------
__global__ __launch_bounds__(256)
void gn_stats_tok_k(const unsigned short* __restrict__ x, float* __restrict__ stats)
{
  __shared__ float sh[8];
  const int mb = blockIdx.x >> 5;   // mod*16+b
  const int g = blockIdx.x & 31;
  const unsigned short* xb = x + (size_t)mb * kHW * kD + g * 16;
  float s = 0.f, s2 = 0.f;
  for (int i = threadIdx.x; i < 800; i += 256) {
    const int p = i >> 1, half = i & 1;
    const s8v u = *(const s8v*)&xb[(size_t)p * kD + half * 8];
#pragma unroll
    for (int j = 0; j < 8; j++) {
      const float v = b2f((unsigned short)u[j]);
      s += v; s2 += v * v;
    }
  }
  breduce2(s, s2, sh);
  if (threadIdx.x == 0) {
    const float mean = s / (kHW * 16.0f);
    const float var  = s2 / (kHW * 16.0f) - mean * mean;
    stats[blockIdx.x * 2]     = mean;
    stats[blockIdx.x * 2 + 1] = rsqrtf(var + kEps);
  }
}

__global__ void gn_norm_tok_k(const unsigned short* __restrict__ x,
                              unsigned short* __restrict__ srcb,
                              const float* __restrict__ stats,
                              const float* __restrict__ gv, const float* __restrict__ bev,
                              const float* __restrict__ gi, const float* __restrict__ bei)
{
  const int gid = blockIdx.x * 256 + threadIdx.x;   // < 12800*64
  const int d0 = (gid & 63) * 8;
  const int rl = gid >> 6;                          // (mod*16+b)*400+p
  const int mb = rl / kHW;
  const int p  = rl - mb * kHW;
  const int mod = mb >> 4, b = mb & 15;
  const int g = d0 >> 4;
  const float mean = stats[(mb * 32 + g) * 2];
  const float rstd = stats[(mb * 32 + g) * 2 + 1];
  const float* gam = mod ? gi : gv;
  const float* bet = mod ? bei : bev;
  const s8v u = *(const s8v*)&x[(size_t)rl * kD + d0];
  const int row = b * kLen + mod * kHW + p;
  s8v o;
#pragma unroll
  for (int j = 0; j < 8; j++)
    o[j] = (short)f2b((b2f((unsigned short)u[j]) - mean) * rstd * gam[d0 + j] + bet[d0 + j]);
  *(s8v*)&srcb[(size_t)row * kD + swzk(row, d0)] = o;
}

// ---------------- GroupNorm (chan-major, bf16 scratch input) ----------------
__global__ __launch_bounds__(256)
void gn_stats_ch_k(const unsigned short* __restrict__ x, float* __restrict__ stats)
{
  __shared__ float sh[8];
  const int b = blockIdx.x >> 5;
  const int g = blockIdx.x & 31;
  const unsigned short* xb = x + (size_t)b * kCin * kHW + (size_t)g * 24 * kHW;
  float s = 0.f, s2 = 0.f;
  for (int i = threadIdx.x; i < 1200; i += 256) {
    const s8v u = *(const s8v*)&xb[(size_t)i * 8];
#pragma unroll
    for (int j = 0; j < 8; j++) {
      const float v = b2f((unsigned short)u[j]);
      s += v; s2 += v * v;
    }
  }
  breduce2(s, s2, sh);
  if (threadIdx.x == 0) {
    const float mean = s / (24.0f * kHW);
    const float var  = s2 / (24.0f * kHW) - mean * mean;
    stats[blockIdx.x * 2]     = mean;
    stats[blockIdx.x * 2 + 1] = rsqrtf(var + kEps);
  }
}

__global__ void gn_norm_ch_k(const unsigned short* __restrict__ x, float* __restrict__ out,
                             const float* __restrict__ stats,
                             const float* __restrict__ gam, const float* __restrict__ bet)
{
  const int gid = blockIdx.x * 256 + threadIdx.x;   // < 16*768*400/8
  const int idx8 = gid * 8;
  const int rest = idx8 / kHW;
  const int c = rest % kCin;
  const int b = rest / kCin;
  const int g = c / 24;
  const float mean = stats[(b * 32 + g) * 2];
  const float rstd = stats[(b * 32 + g) * 2 + 1];
  const float gg = gam[c], bb = bet[c];
  const s8v u = *(const s8v*)&x[idx8];
  float4 o0, o1;
  o0.x = (b2f((unsigned short)u[0]) - mean) * rstd * gg + bb;
  o0.y = (b2f((unsigned short)u[1]) - mean) * rstd * gg + bb;
  o0.z = (b2f((unsigned short)u[2]) - mean) * rstd * gg + bb;
  o0.w = (b2f((unsigned short)u[3]) - mean) * rstd * gg + bb;
  o1.x = (b2f((unsigned short)u[4]) - mean) * rstd * gg + bb;
  o1.y = (b2f((unsigned short)u[5]) - mean) * rstd * gg + bb;
  o1.z = (b2f((unsigned short)u[6]) - mean) * rstd * gg + bb;
  o1.w = (b2f((unsigned short)u[7]) - mean) * rstd * gg + bb;
  *(float4*)(out + idx8)     = o0;
  *(float4*)(out + idx8 + 4) = o1;
}

// ------------- modality-specific LayerNorm (wave/row, bf16 in) --------------
__global__ __launch_bounds__(256)
void ln4_k(const unsigned short* __restrict__ x, unsigned short* __restrict__ outb,
           const float* __restrict__ gamma, const float* __restrict__ beta)
{
  const int row = blockIdx.x * 4 + (threadIdx.x >> 6);
  const int l = threadIdx.x & 63;
  const int mod = ((row % kLen) < kHW) ? 0 : 1;
  const s8v u = *(const s8v*)&x[(size_t)row * kD + l * 8];
  float v[8];
#pragma unroll
  for (int j = 0; j < 8; j++) v[j] = b2f((unsigned short)u[j]);
  float s = 0.f, s2 = 0.f;
#pragma unroll
  for (int j = 0; j < 8; j++) { s += v[j]; s2 += v[j] * v[j]; }
#pragma unroll
  for (int o = 32; o > 0; o >>= 1) {
    s  += __shfl_xor(s, o);
    s2 += __shfl_xor(s2, o);
  }
  const float mean = s * (1.0f / kD);
  const float var  = s2 * (1.0f / kD) - mean * mean;
  const float rstd = rsqrtf(var + kEps);
  const float* g  = gamma + mod * kD + l * 8;
  const float* be = beta  + mod * kD + l * 8;
  s8v o8;
#pragma unroll
  for (int j = 0; j < 8; j++)
    o8[j] = (short)f2b((v[j] - mean) * rstd * g[j] + be[j]);
  *(s8v*)&outb[(size_t)row * kD + swzk(row, l * 8)] = o8;
}

// ------------------- deformable sampling (bf16 value/offaw) -----------------
__global__ __launch_bounds__(256)
void sample_k(const unsigned short* __restrict__ value,
              const unsigned short* __restrict__ offaw,
              unsigned short* __restrict__ out)
{
  __shared__ float wls[2][64][8];   // [tok][combo][w0,i0,...,w3,i3]
  const int tid = threadIdx.x;
  const int tok = tid >> 7;
  const int wt  = tid & 127;
  const int token = blockIdx.x * 2 + tok;       // < 12800
  const int b = token / kLen;
  const int t = token % kLen;
  const int tt = t % kHW;

  if (wt < 64) {
    const int h = wt >> 3, lp = wt & 7, lvl = lp >> 2, p = lp & 3;
    const unsigned short* oa = offaw + (size_t)token * 192;
    const float lg = b2f(oa[128 + h * 8 + lp]);
    float mx = lg;
#pragma unroll
    for (int msk = 1; msk < 8; msk <<= 1) mx = fmaxf(mx, __shfl_xor(mx, msk));
    const float ex = __expf(lg - mx);
    float ssum = ex;
#pragma unroll
    for (int msk = 1; msk < 8; msk <<= 1) ssum += __shfl_xor(ssum, msk);
    const float aw = ex / ssum;

    const float x = (float)(tt % kWpx) + b2f(oa[h * 16 + lvl * 8 + p * 2]);
    const float y = (float)(tt / kWpx) + b2f(oa[h * 16 + lvl * 8 + p * 2 + 1]);
    const float x0f = floorf(x), y0f = floorf(y);
    const float wx = x - x0f, wy = y - y0f;
    const int x0 = (int)x0f, y0 = (int)y0f;
    const int rowbase = b * kLen + lvl * kHW;
#pragma unroll
    for (int dy = 0; dy < 2; dy++) {
#pragma unroll
      for (int dx = 0; dx < 2; dx++) {
        const int ix = x0 + dx, iy = y0 + dy;
        const bool valid = (ix >= 0) & (ix < kWpx) & (iy >= 0) & (iy < kHpx);
        const float cw = (dx ? wx : 1.0f - wx) * (dy ? wy : 1.0f - wy);
        const float w = valid ? aw * cw : 0.0f;
        const int ixc = min(max(ix, 0), kWpx - 1);
        const int iyc = min(max(iy, 0), kHpx - 1);
        const int r = rowbase + iyc * kWpx + ixc;
        const int cn = dy * 2 + dx;
        wls[tok][wt][cn * 2]     = w;
        wls[tok][wt][cn * 2 + 1] = __int_as_float(r);
      }
    }
  }
  __syncthreads();

  const int c0 = wt * 4;
  const int h = wt >> 4;
  float acc0 = 0.f, acc1 = 0.f, acc2 = 0.f, acc3 = 0.f;
  const unsigned short* vb = value + c0;
#pragma unroll
  for (int pp = 0; pp < 8; pp++) {
    const float* wl = wls[tok][h * 8 + pp];
#pragma unroll
    for (int cn = 0; cn < 4; cn++) {
      const float w = wl[cn * 2];
      const int r = __float_as_int(wl[cn * 2 + 1]);
      const s4v q = *(const s4v*)(vb + (size_t)r * kD);
      acc0 += w * b2f((unsigned short)q[0]);
      acc1 += w * b2f((unsigned short)q[1]);
      acc2 += w * b2f((unsigned short)q[2]);
      acc3 += w * b2f((unsigned short)q[3]);
    }
  }
  const int sk = swzk(token, c0);
  s4v o;
  o[0] = (short)f2b(acc0); o[1] = (short)f2b(acc1);
  o[2] = (short)f2b(acc2); o[3] = (short)f2b(acc3);
  *(s4v*)&out[(size_t)token * kD + sk] = o;
}

// -------- token-sum (srcb halves -> tokb swz) + as_w convert, fused ---------
__global__ void sumcvt_k(const unsigned short* __restrict__ srcb,
                         unsigned short* __restrict__ tokb,
                         const float* __restrict__ asw,
                         unsigned short* __restrict__ wcs)
{
  const int bid = blockIdx.x;
  if (bid < 1600) {                              // sumtok: 16*400*64 items
    const int gid = bid * 256 + threadIdx.x;
    const int d0 = (gid & 63) * 8;
    const int rest = gid >> 6;
    const int b = rest / kHW, p = rest % kHW;
    const int r1 = b * kLen + p;
    const int r2 = r1 + kHW;
    const int ro = b * kHW + p;
    const s8v u1 = *(const s8v*)&srcb[(size_t)r1 * kD + swzk(r1, d0)];
    const s8v u2 = *(const s8v*)&srcb[(size_t)r2 * kD + swzk(r2, d0)];
    s8v o;
#pragma unroll
    for (int j = 0; j < 8; j++)
      o[j] = (short)f2b(b2f((unsigned short)u1[j]) + b2f((unsigned short)u2[j]));
    *(s8v*)&tokb[(size_t)ro * kD + swzk(ro, d0)] = o;
    return;
  }
  const int gid = (bid - 1600) * 256 + threadIdx.x;   // < 768*64 (N=768, K=512)
  const int n = gid / 64;
  const int k = (gid % 64) * 8;
  s8v p;
#pragma unroll
  for (int j = 0; j < 8; j++) p[j] = (short)f2b(asw[(size_t)n * kD + k + j]);
  const int base = n * kD + (k & ~31) + ((((k >> 3) + (n >> 1)) & 3) << 3);
  *(s8v*)&wcs[base] = p;
}

// ------------------------------- launcher -----------------------------------
extern "C" void kernel_launch(void* const* d_in, const int* in_sizes, int n_in,
                              void* d_out, int out_size, void* d_ws, size_t ws_size,
                              hipStream_t stream)
{
  const float* input_v     = (const float*)d_in[0];
  const float* input_i     = (const float*)d_in[1];
  const float* av_w        = (const float*)d_in[2];
  const float* av_b        = (const float*)d_in[3];
  const float* av_g        = (const float*)d_in[4];
  const float* av_be       = (const float*)d_in[5];
  const float* ai_w        = (const float*)d_in[6];
  const float* ai_b        = (const float*)d_in[7];
  const float* ai_g        = (const float*)d_in[8];
  const float* ai_be       = (const float*)d_in[9];
  const float* level_embed = (const float*)d_in[10];
  const float* off_w       = (const float*)d_in[11];
  const float* off_b       = (const float*)d_in[12];
  const float* aw_w        = (const float*)d_in[13];
  const float* aw_b        = (const float*)d_in[14];
  const float* vp_w        = (const float*)d_in[15];
  const float* vp_b        = (const float*)d_in[16];
  const float* op_w        = (const float*)d_in[17];
  const float* op_b        = (const float*)d_in[18];
  const float* ln1_g       = (const float*)d_in[19];
  const float* ln1_b       = (const float*)d_in[20];
  const float* ffn1_w      = (const float*)d_in[21];
  const float* ffn1_b      = (const float*)d_in[22];
  const float* ffn2_w      = (const float*)d_in[23];
  const float* ffn2_b      = (const float*)d_in[24];
  const float* ln2_g       = (const float*)d_in[25];
  const float* ln2_b       = (const float*)d_in[26];
  const float* as_w        = (const float*)d_in[27];
  const float* as_b        = (const float*)d_in[28];
  const float* as_g        = (const float*)d_in[29];
  const float* as_be       = (const float*)d_in[30];

  // ------- workspace layout -------
  unsigned short* offawb = (unsigned short*)d_ws;               // 2,457,600 sh
  float* posWc   = (float*)(offawb + 2457600);                  //   921,600 f
  float* biasall = posWc   + (size_t)921600;                    //     1,536 f
  float* stats   = biasall + (size_t)1536;                      //     2,048 f
  unsigned short* srcb     = (unsigned short*)(stats + 2048);   //  6,553,600 sh
  unsigned short* bufA     = srcb     + (size_t)6553600;        // 13,107,200 sh
  unsigned short* bufB     = bufA     + (size_t)13107200;       //  6,553,600 sh
  unsigned short* wall     = bufB     + (size_t)6553600;        // 10,223,616 sh
  unsigned short* wcs      = wall     + (size_t)10223616;       //    786,432 sh
  unsigned short* woaw_all = wcs      + (size_t)786432;         //    786,432 sh
  unsigned short* posfb    = woaw_all + (size_t)786432;         //    458,752 sh
  unsigned short* wallb = wall;   // bf16 conv scratch (aliases weight arena)

  const int M = kB * kLen;   // 12800

  // ---- pre: posfb + woaw + biases (1 dispatch), then posWc GEMM ----
  pre_k<<<dim3(614), 256, 0, stream>>>(level_embed, off_w, aw_w, off_b, aw_b,
                                       posfb, woaw_all, biasall);
  mgemm<5><<<dim3(12, 7), 256, 0, stream>>>(
      posfb, woaw_all, biasall, nullptr, posWc, nullptr, nullptr, nullptr,
      512, 0, 0);

  // ---- input convs (both modalities, one GEMM) + GN -> srcb ----
  tincvt_k<<<dim3(38784), 256, 0, stream>>>(input_v, input_i, av_w, ai_w,
                                            bufA, wcs);
  mgemm<6><<<dim3(4, 100), 256, 0, stream>>>(
      bufA, wcs, av_b, wcs + 393216, nullptr, nullptr, ai_b, bufB, 768, 512, 0);
  gn_stats_tok_k<<<dim3(1024), 256, 0, stream>>>(bufB, stats);
  gn_norm_tok_k<<<dim3(3200), 256, 0, stream>>>(
      bufB, srcb, stats, av_g, av_be, ai_g, ai_be);

  // ---- all layer weights -> wall (one dispatch) ----
  cvt_all_k<<<dim3(4992), 256, 0, stream>>>(vp_w, op_w, off_w, aw_w,
                                            ffn1_w, ffn2_w, wall);

  for (int l = 0; l < kNL; l++) {
    unsigned short* wcomb = wall + (size_t)l * 1703936;
    unsigned short* wop   = wcomb + 393216;
    unsigned short* wf1   = wcomb + 655360;
    unsigned short* wf2   = wcomb + 1179648;
    const float* vbl  = vp_b   + (size_t)l * kD;
    const float* opbl = op_b   + (size_t)l * kD;
    const float* l1g  = ln1_g  + (size_t)l * 2 * kD;
    const float* l1b  = ln1_b  + (size_t)l * 2 * kD;
    const float* f1b  = ffn1_b + (size_t)l * kDff;
    const float* f2b_ = ffn2_b + (size_t)l * kD;
    const float* l2g  = ln2_g  + (size_t)l * 2 * kD;
    const float* l2b  = ln2_b  + (size_t)l * 2 * kD;

    // fused: value bf16 (bufA) | offaw bf16 (+posWc)
    mgemm<4><<<dim3(6, 100), 256, 0, stream>>>(
        srcb, wcomb, vbl, nullptr, nullptr, offawb, posWc + (size_t)l * 153600,
        bufA, 512, 0, 0);

    // sampling -> bufB (bf16 swz)
    sample_k<<<dim3(M / 2), 256, 0, stream>>>(bufA, offawb, bufB);

    // y = srcb + sampled @ op + opb -> bufA (bf16 plain)
    mgemm<2><<<dim3(4, 100), 256, 0, stream>>>(
        bufB, wop, opbl, srcb, nullptr, nullptr, nullptr, bufA, 512, 512, 0);

    // srcb = LN_spec(y)
    ln4_k<<<dim3(M / 4), 256, 0, stream>>>(bufA, srcb, l1g, l1b);

    // FFN full-M: hidden -> bufA (swz, relu); y -> bufB (plain)
    mgemm<1><<<dim3(8, 100), 256, 0, stream>>>(
        srcb, wf1, f1b, nullptr, nullptr, nullptr, nullptr, bufA, 512, 1024, 0);
    mgemm<2><<<dim3(4, 100), 256, 0, stream>>>(
        bufA, wf2, f2b_, srcb, nullptr, nullptr, nullptr, bufB, 1024, 512, 0);

    // srcb = LN_spec(y)
    ln4_k<<<dim3(M / 4), 256, 0, stream>>>(bufB, srcb, l2g, l2b);
  }

  // ---- out = GN(conv1x1(src_v + src_i)); bf16 scratch in wallb ----
  sumcvt_k<<<dim3(1792), 256, 0, stream>>>(srcb, bufA, as_w, wcs);
  mgemm<3><<<dim3(6, 50), 256, 0, stream>>>(
      bufA, wcs, as_b, nullptr, nullptr, nullptr, nullptr, wallb, 512, 0, 768);
  gn_stats_ch_k<<<dim3(kB * 32), 256, 0, stream>>>(wallb, stats);
  gn_norm_ch_k<<<dim3(2400), 256, 0, stream>>>(
      wallb, (float*)d_out, stats, as_g, as_be);
}

// Round 12
// 1063.749 us; speedup vs baseline: 1.1295x; 1.0053x over previous
//
#include <hip/hip_runtime.h>
#include <hip/hip_bf16.h>
#include <cstddef>
#include <math.h>

// ---------------------------------------------------------------------------
// Round 11: round-8/10 structure (best 1068-1069 us) + init-path cleanup:
// input transpose now 128ch x 16pos tiles with vectorized s8v swizzled writes
// (was 38400 blocks w/ scalar 2B stores), and ALL init work (transpose, conv
// weight cvt, positional feats, oaw weights, per-layer weight cvt) fused into
// ONE init_k dispatch. GEMM/layer structure untouched.
// ---------------------------------------------------------------------------

constexpr int kB   = 16;
constexpr int kCin = 768;
constexpr int kHW  = 400;
constexpr int kWpx = 20;
constexpr int kHpx = 20;
constexpr int kD   = 512;
constexpr int kLen = 800;
constexpr int kDff = 1024;
constexpr int kNL  = 6;
constexpr float kEps = 1e-5f;

typedef __attribute__((ext_vector_type(8))) short s8v;
typedef __attribute__((ext_vector_type(4))) short s4v;
typedef __attribute__((ext_vector_type(4))) float f4v;

__device__ __forceinline__ int swzk(int row, int k) {
  return (k & ~31) | ((((k >> 3) + (row >> 1)) & 3) << 3) | (k & 7);
}

__device__ __forceinline__ unsigned short f2b(float f) {
  union { __hip_bfloat16 h; unsigned short u; } cv;
  cv.h = __float2bfloat16(f);
  return cv.u;
}

__device__ __forceinline__ float b2f(unsigned short u) {
  return __uint_as_float(((unsigned)u) << 16);
}

__device__ __forceinline__ void gll(const unsigned short* g, unsigned short* l) {
  __builtin_amdgcn_global_load_lds(
      (const __attribute__((address_space(1))) unsigned int*)g,
      (__attribute__((address_space(3))) unsigned int*)l, 16, 0, 0);
}

// ------------------------------ block reduce -------------------------------
__device__ __forceinline__ void breduce2(float& s, float& s2, float* sh) {
#pragma unroll
  for (int o = 32; o > 0; o >>= 1) {
    s  += __shfl_down(s, o);
    s2 += __shfl_down(s2, o);
  }
  const int wid = threadIdx.x >> 6, lane = threadIdx.x & 63;
  if (lane == 0) { sh[wid] = s; sh[4 + wid] = s2; }
  __syncthreads();
  if (threadIdx.x == 0) {
    sh[0] = sh[0] + sh[1] + sh[2] + sh[3];
    sh[4] = sh[4] + sh[5] + sh[6] + sh[7];
  }
  __syncthreads();
  s = sh[0]; s2 = sh[4];
}

// ------------------------------- MFMA GEMM ---------------------------------
// EPI 1: bf16 Cb[row*ldc + swzk] = relu(acc+bias)            (ffn hidden)
// EPI 2: bf16 Cb[row*512+col] = acc+bias + res(srcb swz)     (pre-LN y)
// EPI 3: bf16 Cb[((row/400)*Nreal+col)*400 + row%400] = acc+bias (conv out)
// EPI 4: col<512 -> bf16 Cb[row*512+col] (value, plain);
//        col in [512,704) -> bf16 Cb2[row*192+c] = acc + aux[(row%800)*192+c]
// EPI 5: posWc writer: Cf[((col>>8)*800 + row)*192 + (col&255)] = acc+bias
// EPI 6: plain bf16 Cb[row*512+col]; rows >= 6400 use resb/aux as W/bias
template<int EPI>
__global__ __launch_bounds__(256)
void mgemm(const unsigned short* __restrict__ Abf,
           const unsigned short* __restrict__ Bw,
           const float* __restrict__ bias,
           const unsigned short* __restrict__ resb,
           float* __restrict__ Cf, unsigned short* __restrict__ Cb2,
           const float* __restrict__ aux,
           unsigned short* __restrict__ Cb,
           int K, int ldc, int Nreal)
{
  __shared__ unsigned short As[3][4096];
  __shared__ unsigned short Bs[3][4096];
  const int tid = threadIdx.x;
  const int w = tid >> 6, l = tid & 63;

  // bijective XCD-aware swizzle (m204)
  const int gx = gridDim.x;
  const int nwg = gx * gridDim.y;
  const int bid = blockIdx.y * gx + blockIdx.x;
  const int q = nwg >> 3, r = nwg & 7;
  const int xcd = bid & 7, idx = bid >> 3;
  const int wgid = (xcd < r ? xcd * (q + 1) : r * (q + 1) + (xcd - r) * q) + idx;
  const int m0 = (wgid / gx) * 128;
  const int n0 = (wgid % gx) * 128;

  if (EPI == 6 && m0 >= 6400) { Bw = resb; bias = aux; }

  f4v acc[4][4] = {};

  const int srow = w * 32 + (l >> 2);
  const unsigned short* ga0 = Abf + (size_t)(m0 + srow) * K + (l & 3) * 8;
  const unsigned short* ga1 = ga0 + (size_t)16 * K;
  const unsigned short* gb0 = Bw + (size_t)(n0 + srow) * K + (l & 3) * 8;
  const unsigned short* gb1 = gb0 + (size_t)16 * K;
  const int lb0 = (w * 32) * 32;
  const int lb1 = (w * 32 + 16) * 32;

  int aoff[4], boff[4];
#pragma unroll
  for (int f = 0; f < 4; f++) {
    const int ra = (w >> 1) * 64 + f * 16 + (l & 15);
    aoff[f] = ra * 32 + ((((l >> 4) + (ra >> 1)) & 3) << 3);
    const int rb = (w & 1) * 64 + f * 16 + (l & 15);
    boff[f] = rb * 32 + ((((l >> 4) + (rb >> 1)) & 3) << 3);
  }

#define STAGEG(ko, bi) do { \
    gll(ga0 + (ko), &As[bi][lb0]); gll(ga1 + (ko), &As[bi][lb1]); \
    gll(gb0 + (ko), &Bs[bi][lb0]); gll(gb1 + (ko), &Bs[bi][lb1]); } while (0)

  const int NT = K >> 5;
  STAGEG(0, 0);
  STAGEG(32, 1);

  int cur = 0;
  int bpre = 2;
  int kpre = 64;
  for (int t = 0; t < NT; ++t) {
    if (t + 1 < NT) asm volatile("s_waitcnt vmcnt(4)" ::: "memory");
    else            asm volatile("s_waitcnt vmcnt(0)" ::: "memory");
    __builtin_amdgcn_s_barrier();
    __builtin_amdgcn_sched_barrier(0);
    if (t + 2 < NT) STAGEG(kpre, bpre);
    s8v af[4], bf4[4];
#pragma unroll
    for (int f = 0; f < 4; f++) {
      af[f]  = *(const s8v*)&As[cur][aoff[f]];
      bf4[f] = *(const s8v*)&Bs[cur][boff[f]];
    }
    __builtin_amdgcn_s_setprio(1);
#pragma unroll
    for (int i = 0; i < 4; i++)
#pragma unroll
      for (int j = 0; j < 4; j++)
        acc[i][j] = __builtin_amdgcn_mfma_f32_16x16x32_bf16(af[i], bf4[j], acc[i][j], 0, 0, 0);
    __builtin_amdgcn_s_setprio(0);
    kpre += 32;
    bpre = (bpre == 2) ? 0 : bpre + 1;
    cur  = (cur == 2) ? 0 : cur + 1;
  }
#undef STAGEG

  // C/D layout: col=lane&15, row=(lane>>4)*4+reg
  const int colb = n0 + (w & 1) * 64;
  const int rowb = m0 + (w >> 1) * 64 + (l >> 4) * 4;
#pragma unroll
  for (int i = 0; i < 4; i++) {
#pragma unroll
    for (int j = 0; j < 4; j++) {
      const int col = colb + j * 16 + (l & 15);
      float bv;
      if (EPI == 4) bv = (col < kD) ? bias[col] : 0.0f;
      else          bv = bias[col];
#pragma unroll
      for (int r2 = 0; r2 < 4; r2++) {
        const int row = rowb + i * 16 + r2;
        float v = acc[i][j][r2] + bv;
        if (EPI == 1) {
          Cb[(size_t)row * ldc + swzk(row, col)] = f2b(fmaxf(v, 0.0f));
        } else if (EPI == 2) {
          v += b2f(resb[(size_t)row * kD + swzk(row, col)]);
          Cb[(size_t)row * kD + col] = f2b(v);
        } else if (EPI == 3) {
          const int bb = row / kHW, p = row % kHW;
          Cb[((size_t)bb * Nreal + col) * kHW + p] = f2b(v);
        } else if (EPI == 4) {
          if (col < kD) {
            Cb[(size_t)row * kD + col] = f2b(v);
          } else {
            const int c = col - kD;
            if (c < 192)
              Cb2[(size_t)row * 192 + c] = f2b(v + aux[(size_t)(row % kLen) * 192 + c]);
          }
        } else if (EPI == 5) {
          if (row < kLen) {
            const int ll = col >> 8, c = col & 255;
            if (c < 192)
              Cf[(((size_t)ll * kLen) + row) * 192 + c] = v;
          }
        } else {  // EPI == 6
          Cb[(size_t)row * kD + col] = f2b(v);
        }
      }
    }
  }
}

// -------------------------- weight conversions -----------------------------
__device__ __forceinline__ void cvt8t(const float* __restrict__ W,
                                      unsigned short* __restrict__ out,
                                      int K, int N, int g)
{
  const int n = g % N;
  const int k = (g / N) * 8;
  s8v p;
#pragma unroll
  for (int j = 0; j < 8; j++) p[j] = (short)f2b(W[(size_t)(k + j) * N + n]);
  const int base = n * K + (k & ~31) + ((((k >> 3) + (n >> 1)) & 3) << 3);
  *(s8v*)&out[base] = p;
}

// ---------------------- ALL init work, one dispatch -------------------------
// sections (blockIdx ranges):
//   [0, 4800)        input transpose: 128ch x 16pos tiles, s8v swz writes
//   [4800, 5184)     both input conv weights -> wcs
//   [5184, 5798)     posfb + woaw_all + biasall  (pre)
//   [5798, 10790)    all 6 layers' weights -> wall (832 blocks/layer)
__global__ __launch_bounds__(256)
void init_k(const float* __restrict__ inv, const float* __restrict__ ini,
            const float* __restrict__ W0, const float* __restrict__ W1,
            const float* __restrict__ level_embed,
            const float* __restrict__ off_w, const float* __restrict__ aw_w,
            const float* __restrict__ off_b, const float* __restrict__ aw_b,
            const float* __restrict__ vp_w, const float* __restrict__ op_w,
            const float* __restrict__ f1w_a, const float* __restrict__ f2w_a,
            unsigned short* __restrict__ tin_out, unsigned short* __restrict__ wcs,
            unsigned short* __restrict__ posfb, unsigned short* __restrict__ woaw_all,
            float* __restrict__ biasall, unsigned short* __restrict__ wall)
{
  __shared__ float t[128][17];
  int bid = blockIdx.x;

  if (bid < 4800) {                     // ---- input transpose ----
    const int z = bid / 150;            // mod*16+b
    const int rem = bid % 150;
    const int c0 = (rem / 25) * 128;
    const int p0 = (rem % 25) * 16;
    const int mod = z >> 4, b = z & 15;
    const float* in = (mod ? ini : inv) + (size_t)b * kCin * kHW;
    const int j  = threadIdx.x & 15;    // position
    const int i0 = threadIdx.x >> 4;    // channel octet
#pragma unroll
    for (int ii = 0; ii < 8; ii++) {
      const int i = i0 * 8 + ii;
      t[i][j] = in[(size_t)(c0 + i) * kHW + p0 + j];
    }
    __syncthreads();
    const int p   = threadIdx.x >> 4;
    const int oct = threadIdx.x & 15;
    const int row = z * kHW + p0 + p;
    const int c   = c0 + oct * 8;
    s8v o;
#pragma unroll
    for (int cc = 0; cc < 8; cc++) o[cc] = (short)f2b(t[oct * 8 + cc][p]);
    *(s8v*)&tin_out[(size_t)row * kCin + swzk(row, c)] = o;
    return;
  }
  bid -= 4800;

  if (bid < 384) {                      // ---- conv weights (av, ai) ----
    int gid = bid * 256 + threadIdx.x;  // < 2*512*96
    const float* W = W0;
    unsigned short* o = wcs;
    if (gid >= 49152) { gid -= 49152; W = W1; o = wcs + 393216; }
    const int n = gid / 96;
    const int k = (gid % 96) * 8;
    s8v p;
#pragma unroll
    for (int j = 0; j < 8; j++) p[j] = (short)f2b(W[(size_t)n * kCin + k + j]);
    const int base = n * kCin + (k & ~31) + ((((k >> 3) + (n >> 1)) & 3) << 3);
    *(s8v*)&o[base] = p;
    return;
  }
  bid -= 384;

  if (bid < 614) {                      // ---- pre: posfb + woaw + biases ----
    int g = bid * 256 + threadIdx.x;
    if (g < 57344) {                    // posfb: 896*64
      const int d0 = (g & 63) * 8;
      const int tt2 = g >> 6;
      s8v o;
      if (tt2 >= kLen) {
#pragma unroll
        for (int j = 0; j < 8; j++) o[j] = 0;
      } else {
        const int lvl = tt2 / kHW;
        const int tt = tt2 % kHW;
        const int yy = tt / kWpx, xx = tt % kWpx;
#pragma unroll
        for (int j = 0; j < 8; j++) {
          const int d = d0 + j;
          const int dd = d & 255;
          const float e = (d < 256) ? ((float)(yy + 1) * (6.283185307179586f / kHpx))
                                    : ((float)(xx + 1) * (6.283185307179586f / kWpx));
          const float dimt = powf(10000.0f, (float)(dd >> 1) / 128.0f);
          const float pp = e / dimt;
          const float val = (dd & 1) ? cosf(pp) : sinf(pp);
          o[j] = (short)f2b(val + level_embed[lvl * kD + d]);
        }
      }
      *(s8v*)&posfb[(size_t)tt2 * kD + swzk(tt2, d0)] = o;
      return;
    }
    g -= 57344;
    if (g < 98304) {                    // woaw_all
      const int l = g >> 14;
      const int gg = g & 16383;
      const int n = gg & 255;
      const int k = (gg >> 8) * 8;
      const float* ow = off_w + (size_t)l * kD * 128;
      const float* aww = aw_w + (size_t)l * kD * 64;
      s8v p;
#pragma unroll
      for (int j = 0; j < 8; j++) {
        float v = 0.0f;
        if (n < 128)      v = ow[(size_t)(k + j) * 128 + n];
        else if (n < 192) v = aww[(size_t)(k + j) * 64 + (n - 128)];
        p[j] = (short)f2b(v);
      }
      const int row = l * 256 + n;
      const int base = row * 512 + (k & ~31) + ((((k >> 3) + (row >> 1)) & 3) << 3);
      *(s8v*)&woaw_all[base] = p;
      return;
    }
    g -= 98304;                         // biasall < 1536
    if (g < 1536) {
      const int l = g >> 8, c = g & 255;
      float v = 0.0f;
      if (c < 128)      v = off_b[l * 128 + c];
      else if (c < 192) v = aw_b[l * 64 + (c - 128)];
      biasall[l * 256 + c] = v;
    }
    return;
  }
  bid -= 614;

  {                                     // ---- all layer weights -> wall ----
    const int lyr = bid / 832;
    int g = (bid % 832) * 256 + threadIdx.x;
    unsigned short* wl = wall + (size_t)lyr * 1703936;
    if (g < 32768) { cvt8t(vp_w + (size_t)lyr * kD * kD, wl, 512, 512, g); return; }
    g -= 32768;
    if (g < 16384) {                    // [ow|aww] -> wcomb rows 512..767
      const int n = g & 255;
      const int k = (g >> 8) * 8;
      const float* ow  = off_w + (size_t)lyr * kD * 128;
      const float* aww = aw_w  + (size_t)lyr * kD * 64;
      s8v p;
#pragma unroll
      for (int j = 0; j < 8; j++) {
        float v = 0.0f;
        if (n < 128)      v = ow[(size_t)(k + j) * 128 + n];
        else if (n < 192) v = aww[(size_t)(k + j) * 64 + (n - 128)];
        p[j] = (short)f2b(v);
      }
      const int row = 512 + n;
      const int base = row * 512 + (k & ~31) + ((((k >> 3) + (row >> 1)) & 3) << 3);
      *(s8v*)&wl[base] = p;
      return;
    }
    g -= 16384;
    if (g < 32768) { cvt8t(op_w + (size_t)lyr * kD * kD, wl + 393216, 512, 512, g); return; }
    g -= 32768;
    if (g < 65536) { cvt8t(f1w_a + (size_t)lyr * kD * kDff, wl + 655360, 512, 1024, g); return; }
    g -= 65536;
    cvt8t(f2w_a + (size_t)lyr * kDff * kD, wl + 1179648, 1024, 512, g);
  }
}

// ------------------ GroupNorm (token-major, bf16 input) ---------------------
__global__ __launch_bounds__(256)
void gn_stats_tok_k(const unsigned short* __restrict__ x, float* __restrict__ stats)
{
  __shared__ float sh[8];
  const int mb = blockIdx.x >> 5;   // mod*16+b
  const int g = blockIdx.x & 31;
  const unsigned short* xb = x + (size_t)mb * kHW * kD + g * 16;
  float s = 0.f, s2 = 0.f;
  for (int i = threadIdx.x; i < 800; i += 256) {
    const int p = i >> 1, half = i & 1;
    const s8v u = *(const s8v*)&xb[(size_t)p * kD + half * 8];
#pragma unroll
    for (int j = 0; j < 8; j++) {
      const float v = b2f((unsigned short)u[j]);
      s += v; s2 += v * v;
    }
  }
  breduce2(s, s2, sh);
  if (threadIdx.x == 0) {
    const float mean = s / (kHW * 16.0f);
    const float var  = s2 / (kHW * 16.0f) - mean * mean;
    stats[blockIdx.x * 2]     = mean;
    stats[blockIdx.x * 2 + 1] = rsqrtf(var + kEps);
  }
}

__global__ void gn_norm_tok_k(const unsigned short* __restrict__ x,
                              unsigned short* __restrict__ srcb,
                              const float* __restrict__ stats,
                              const float* __restrict__ gv, const float* __restrict__ bev,
                              const float* __restrict__ gi, const float* __restrict__ bei)
{
  const int gid = blockIdx.x * 256 + threadIdx.x;   // < 12800*64
  const int d0 = (gid & 63) * 8;
  const int rl = gid >> 6;                          // (mod*16+b)*400+p
  const int mb = rl / kHW;
  const int p  = rl - mb * kHW;
  const int mod = mb >> 4, b = mb & 15;
  const int g = d0 >> 4;
  const float mean = stats[(mb * 32 + g) * 2];
  const float rstd = stats[(mb * 32 + g) * 2 + 1];
  const float* gam = mod ? gi : gv;
  const float* bet = mod ? bei : bev;
  const s8v u = *(const s8v*)&x[(size_t)rl * kD + d0];
  const int row = b * kLen + mod * kHW + p;
  s8v o;
#pragma unroll
  for (int j = 0; j < 8; j++)
    o[j] = (short)f2b((b2f((unsigned short)u[j]) - mean) * rstd * gam[d0 + j] + bet[d0 + j]);
  *(s8v*)&srcb[(size_t)row * kD + swzk(row, d0)] = o;
}

// ---------------- GroupNorm (chan-major, bf16 scratch input) ----------------
__global__ __launch_bounds__(256)
void gn_stats_ch_k(const unsigned short* __restrict__ x, float* __restrict__ stats)
{
  __shared__ float sh[8];
  const int b = blockIdx.x >> 5;
  const int g = blockIdx.x & 31;
  const unsigned short* xb = x + (size_t)b * kCin * kHW + (size_t)g * 24 * kHW;
  float s = 0.f, s2 = 0.f;
  for (int i = threadIdx.x; i < 1200; i += 256) {
    const s8v u = *(const s8v*)&xb[(size_t)i * 8];
#pragma unroll
    for (int j = 0; j < 8; j++) {
      const float v = b2f((unsigned short)u[j]);
      s += v; s2 += v * v;
    }
  }
  breduce2(s, s2, sh);
  if (threadIdx.x == 0) {
    const float mean = s / (24.0f * kHW);
    const float var  = s2 / (24.0f * kHW) - mean * mean;
    stats[blockIdx.x * 2]     = mean;
    stats[blockIdx.x * 2 + 1] = rsqrtf(var + kEps);
  }
}

__global__ void gn_norm_ch_k(const unsigned short* __restrict__ x, float* __restrict__ out,
                             const float* __restrict__ stats,
                             const float* __restrict__ gam, const float* __restrict__ bet)
{
  const int gid = blockIdx.x * 256 + threadIdx.x;   // < 16*768*400/8
  const int idx8 = gid * 8;
  const int rest = idx8 / kHW;
  const int c = rest % kCin;
  const int b = rest / kCin;
  const int g = c / 24;
  const float mean = stats[(b * 32 + g) * 2];
  const float rstd = stats[(b * 32 + g) * 2 + 1];
  const float gg = gam[c], bb = bet[c];
  const s8v u = *(const s8v*)&x[idx8];
  float4 o0, o1;
  o0.x = (b2f((unsigned short)u[0]) - mean) * rstd * gg + bb;
  o0.y = (b2f((unsigned short)u[1]) - mean) * rstd * gg + bb;
  o0.z = (b2f((unsigned short)u[2]) - mean) * rstd * gg + bb;
  o0.w = (b2f((unsigned short)u[3]) - mean) * rstd * gg + bb;
  o1.x = (b2f((unsigned short)u[4]) - mean) * rstd * gg + bb;
  o1.y = (b2f((unsigned short)u[5]) - mean) * rstd * gg + bb;
  o1.z = (b2f((unsigned short)u[6]) - mean) * rstd * gg + bb;
  o1.w = (b2f((unsigned short)u[7]) - mean) * rstd * gg + bb;
  *(float4*)(out + idx8)     = o0;
  *(float4*)(out + idx8 + 4) = o1;
}

// ------------- modality-specific LayerNorm (wave/row, bf16 in) --------------
__global__ __launch_bounds__(256)
void ln4_k(const unsigned short* __restrict__ x, unsigned short* __restrict__ outb,
           const float* __restrict__ gamma, const float* __restrict__ beta)
{
  const int row = blockIdx.x * 4 + (threadIdx.x >> 6);
  const int l = threadIdx.x & 63;
  const int mod = ((row % kLen) < kHW) ? 0 : 1;
  const s8v u = *(const s8v*)&x[(size_t)row * kD + l * 8];
  float v[8];
#pragma unroll
  for (int j = 0; j < 8; j++) v[j] = b2f((unsigned short)u[j]);
  float s = 0.f, s2 = 0.f;
#pragma unroll
  for (int j = 0; j < 8; j++) { s += v[j]; s2 += v[j] * v[j]; }
#pragma unroll
  for (int o = 32; o > 0; o >>= 1) {
    s  += __shfl_xor(s, o);
    s2 += __shfl_xor(s2, o);
  }
  const float mean = s * (1.0f / kD);
  const float var  = s2 * (1.0f / kD) - mean * mean;
  const float rstd = rsqrtf(var + kEps);
  const float* g  = gamma + mod * kD + l * 8;
  const float* be = beta  + mod * kD + l * 8;
  s8v o8;
#pragma unroll
  for (int j = 0; j < 8; j++)
    o8[j] = (short)f2b((v[j] - mean) * rstd * g[j] + be[j]);
  *(s8v*)&outb[(size_t)row * kD + swzk(row, l * 8)] = o8;
}

// ------------------- deformable sampling (bf16 value/offaw) -----------------
__global__ __launch_bounds__(256)
void sample_k(const unsigned short* __restrict__ value,
              const unsigned short* __restrict__ offaw,
              unsigned short* __restrict__ out)
{
  __shared__ float wls[2][64][8];   // [tok][combo][w0,i0,...,w3,i3]
  const int tid = threadIdx.x;
  const int tok = tid >> 7;
  const int wt  = tid & 127;
  const int token = blockIdx.x * 2 + tok;       // < 12800
  const int b = token / kLen;
  const int t = token % kLen;
  const int tt = t % kHW;

  if (wt < 64) {
    const int h = wt >> 3, lp = wt & 7, lvl = lp >> 2, p = lp & 3;
    const unsigned short* oa = offaw + (size_t)token * 192;
    const float lg = b2f(oa[128 + h * 8 + lp]);
    float mx = lg;
#pragma unroll
    for (int msk = 1; msk < 8; msk <<= 1) mx = fmaxf(mx, __shfl_xor(mx, msk));
    const float ex = __expf(lg - mx);
    float ssum = ex;
#pragma unroll
    for (int msk = 1; msk < 8; msk <<= 1) ssum += __shfl_xor(ssum, msk);
    const float aw = ex / ssum;

    const float x = (float)(tt % kWpx) + b2f(oa[h * 16 + lvl * 8 + p * 2]);
    const float y = (float)(tt / kWpx) + b2f(oa[h * 16 + lvl * 8 + p * 2 + 1]);
    const float x0f = floorf(x), y0f = floorf(y);
    const float wx = x - x0f, wy = y - y0f;
    const int x0 = (int)x0f, y0 = (int)y0f;
    const int rowbase = b * kLen + lvl * kHW;
#pragma unroll
    for (int dy = 0; dy < 2; dy++) {
#pragma unroll
      for (int dx = 0; dx < 2; dx++) {
        const int ix = x0 + dx, iy = y0 + dy;
        const bool valid = (ix >= 0) & (ix < kWpx) & (iy >= 0) & (iy < kHpx);
        const float cw = (dx ? wx : 1.0f - wx) * (dy ? wy : 1.0f - wy);
        const float w = valid ? aw * cw : 0.0f;
        const int ixc = min(max(ix, 0), kWpx - 1);
        const int iyc = min(max(iy, 0), kHpx - 1);
        const int r = rowbase + iyc * kWpx + ixc;
        const int cn = dy * 2 + dx;
        wls[tok][wt][cn * 2]     = w;
        wls[tok][wt][cn * 2 + 1] = __int_as_float(r);
      }
    }
  }
  __syncthreads();

  const int c0 = wt * 4;
  const int h = wt >> 4;
  float acc0 = 0.f, acc1 = 0.f, acc2 = 0.f, acc3 = 0.f;
  const unsigned short* vb = value + c0;
#pragma unroll
  for (int pp = 0; pp < 8; pp++) {
    const float* wl = wls[tok][h * 8 + pp];
#pragma unroll
    for (int cn = 0; cn < 4; cn++) {
      const float w = wl[cn * 2];
      const int r = __float_as_int(wl[cn * 2 + 1]);
      const s4v q = *(const s4v*)(vb + (size_t)r * kD);
      acc0 += w * b2f((unsigned short)q[0]);
      acc1 += w * b2f((unsigned short)q[1]);
      acc2 += w * b2f((unsigned short)q[2]);
      acc3 += w * b2f((unsigned short)q[3]);
    }
  }
  const int sk = swzk(token, c0);
  s4v o;
  o[0] = (short)f2b(acc0); o[1] = (short)f2b(acc1);
  o[2] = (short)f2b(acc2); o[3] = (short)f2b(acc3);
  *(s4v*)&out[(size_t)token * kD + sk] = o;
}

// -------- token-sum (srcb halves -> tokb swz) + as_w convert, fused ---------
__global__ void sumcvt_k(const unsigned short* __restrict__ srcb,
                         unsigned short* __restrict__ tokb,
                         const float* __restrict__ asw,
                         unsigned short* __restrict__ wcs)
{
  const int bid = blockIdx.x;
  if (bid < 1600) {                              // sumtok: 16*400*64 items
    const int gid = bid * 256 + threadIdx.x;
    const int d0 = (gid & 63) * 8;
    const int rest = gid >> 6;
    const int b = rest / kHW, p = rest % kHW;
    const int r1 = b * kLen + p;
    const int r2 = r1 + kHW;
    const int ro = b * kHW + p;
    const s8v u1 = *(const s8v*)&srcb[(size_t)r1 * kD + swzk(r1, d0)];
    const s8v u2 = *(const s8v*)&srcb[(size_t)r2 * kD + swzk(r2, d0)];
    s8v o;
#pragma unroll
    for (int j = 0; j < 8; j++)
      o[j] = (short)f2b(b2f((unsigned short)u1[j]) + b2f((unsigned short)u2[j]));
    *(s8v*)&tokb[(size_t)ro * kD + swzk(ro, d0)] = o;
    return;
  }
  const int gid = (bid - 1600) * 256 + threadIdx.x;   // < 768*64 (N=768, K=512)
  const int n = gid / 64;
  const int k = (gid % 64) * 8;
  s8v p;
#pragma unroll
  for (int j = 0; j < 8; j++) p[j] = (short)f2b(asw[(size_t)n * kD + k + j]);
  const int base = n * kD + (k & ~31) + ((((k >> 3) + (n >> 1)) & 3) << 3);
  *(s8v*)&wcs[base] = p;
}

// ------------------------------- launcher -----------------------------------
extern "C" void kernel_launch(void* const* d_in, const int* in_sizes, int n_in,
                              void* d_out, int out_size, void* d_ws, size_t ws_size,
                              hipStream_t stream)
{
  const float* input_v     = (const float*)d_in[0];
  const float* input_i     = (const float*)d_in[1];
  const float* av_w        = (const float*)d_in[2];
  const float* av_b        = (const float*)d_in[3];
  const float* av_g        = (const float*)d_in[4];
  const float* av_be       = (const float*)d_in[5];
  const float* ai_w        = (const float*)d_in[6];
  const float* ai_b        = (const float*)d_in[7];
  const float* ai_g        = (const float*)d_in[8];
  const float* ai_be       = (const float*)d_in[9];
  const float* level_embed = (const float*)d_in[10];
  const float* off_w       = (const float*)d_in[11];
  const float* off_b       = (const float*)d_in[12];
  const float* aw_w        = (const float*)d_in[13];
  const float* aw_b        = (const float*)d_in[14];
  const float* vp_w        = (const float*)d_in[15];
  const float* vp_b        = (const float*)d_in[16];
  const float* op_w        = (const float*)d_in[17];
  const float* op_b        = (const float*)d_in[18];
  const float* ln1_g       = (const float*)d_in[19];
  const float* ln1_b       = (const float*)d_in[20];
  const float* ffn1_w      = (const float*)d_in[21];
  const float* ffn1_b      = (const float*)d_in[22];
  const float* ffn2_w      = (const float*)d_in[23];
  const float* ffn2_b      = (const float*)d_in[24];
  const float* ln2_g       = (const float*)d_in[25];
  const float* ln2_b       = (const float*)d_in[26];
  const float* as_w        = (const float*)d_in[27];
  const float* as_b        = (const float*)d_in[28];
  const float* as_g        = (const float*)d_in[29];
  const float* as_be       = (const float*)d_in[30];

  // ------- workspace layout -------
  unsigned short* offawb = (unsigned short*)d_ws;               // 2,457,600 sh
  float* posWc   = (float*)(offawb + 2457600);                  //   921,600 f
  float* biasall = posWc   + (size_t)921600;                    //     1,536 f
  float* stats   = biasall + (size_t)1536;                      //     2,048 f
  unsigned short* srcb     = (unsigned short*)(stats + 2048);   //  6,553,600 sh
  unsigned short* bufA     = srcb     + (size_t)6553600;        // 13,107,200 sh
  unsigned short* bufB     = bufA     + (size_t)13107200;       //  6,553,600 sh
  unsigned short* wall     = bufB     + (size_t)6553600;        // 10,223,616 sh
  unsigned short* wcs      = wall     + (size_t)10223616;       //    786,432 sh
  unsigned short* woaw_all = wcs      + (size_t)786432;         //    786,432 sh
  unsigned short* posfb    = woaw_all + (size_t)786432;         //    458,752 sh
  unsigned short* wallb = wall;   // bf16 conv scratch (aliases weight arena)

  const int M = kB * kLen;   // 12800

  // ---- ALL init work (transpose, weight cvts, pos feats) in one dispatch ----
  init_k<<<dim3(10790), 256, 0, stream>>>(
      input_v, input_i, av_w, ai_w, level_embed, off_w, aw_w, off_b, aw_b,
      vp_w, op_w, ffn1_w, ffn2_w,
      bufA, wcs, posfb, woaw_all, biasall, wall);

  // posWc = posf @ [ow|aww] + bias
  mgemm<5><<<dim3(12, 7), 256, 0, stream>>>(
      posfb, woaw_all, biasall, nullptr, posWc, nullptr, nullptr, nullptr,
      512, 0, 0);

  // ---- input convs (both modalities, one GEMM) + GN -> srcb ----
  mgemm<6><<<dim3(4, 100), 256, 0, stream>>>(
      bufA, wcs, av_b, wcs + 393216, nullptr, nullptr, ai_b, bufB, 768, 512, 0);
  gn_stats_tok_k<<<dim3(1024), 256, 0, stream>>>(bufB, stats);
  gn_norm_tok_k<<<dim3(3200), 256, 0, stream>>>(
      bufB, srcb, stats, av_g, av_be, ai_g, ai_be);

  for (int l = 0; l < kNL; l++) {
    unsigned short* wcomb = wall + (size_t)l * 1703936;
    unsigned short* wop   = wcomb + 393216;
    unsigned short* wf1   = wcomb + 655360;
    unsigned short* wf2   = wcomb + 1179648;
    const float* vbl  = vp_b   + (size_t)l * kD;
    const float* opbl = op_b   + (size_t)l * kD;
    const float* l1g  = ln1_g  + (size_t)l * 2 * kD;
    const float* l1b  = ln1_b  + (size_t)l * 2 * kD;
    const float* f1b  = ffn1_b + (size_t)l * kDff;
    const float* f2b_ = ffn2_b + (size_t)l * kD;
    const float* l2g  = ln2_g  + (size_t)l * 2 * kD;
    const float* l2b  = ln2_b  + (size_t)l * 2 * kD;

    // fused: value bf16 (bufA) | offaw bf16 (+posWc)
    mgemm<4><<<dim3(6, 100), 256, 0, stream>>>(
        srcb, wcomb, vbl, nullptr, nullptr, offawb, posWc + (size_t)l * 153600,
        bufA, 512, 0, 0);

    // sampling -> bufB (bf16 swz)
    sample_k<<<dim3(M / 2), 256, 0, stream>>>(bufA, offawb, bufB);

    // y = srcb + sampled @ op + opb -> bufA (bf16 plain)
    mgemm<2><<<dim3(4, 100), 256, 0, stream>>>(
        bufB, wop, opbl, srcb, nullptr, nullptr, nullptr, bufA, 512, 512, 0);

    // srcb = LN_spec(y)
    ln4_k<<<dim3(M / 4), 256, 0, stream>>>(bufA, srcb, l1g, l1b);

    // FFN full-M: hidden -> bufA (swz, relu); y -> bufB (plain)
    mgemm<1><<<dim3(8, 100), 256, 0, stream>>>(
        srcb, wf1, f1b, nullptr, nullptr, nullptr, nullptr, bufA, 512, 1024, 0);
    mgemm<2><<<dim3(4, 100), 256, 0, stream>>>(
        bufA, wf2, f2b_, srcb, nullptr, nullptr, nullptr, bufB, 1024, 512, 0);

    // srcb = LN_spec(y)
    ln4_k<<<dim3(M / 4), 256, 0, stream>>>(bufB, srcb, l2g, l2b);
  }

  // ---- out = GN(conv1x1(src_v + src_i)); bf16 scratch in wallb ----
  sumcvt_k<<<dim3(1792), 256, 0, stream>>>(srcb, bufA, as_w, wcs);
  mgemm<3><<<dim3(6, 50), 256, 0, stream>>>(
      bufA, wcs, as_b, nullptr, nullptr, nullptr, nullptr, wallb, 512, 0, 768);
  gn_stats_ch_k<<<dim3(kB * 32), 256, 0, stream>>>(wallb, stats);
  gn_norm_ch_k<<<dim3(2400), 256, 0, stream>>>(
      wallb, (float*)d_out, stats, as_g, as_be);
}

// Round 13
// 1061.377 us; speedup vs baseline: 1.1321x; 1.0022x over previous
//
#include <hip/hip_runtime.h>
#include <hip/hip_bf16.h>
#include <cstddef>
#include <math.h>

// ---------------------------------------------------------------------------
// Round 12: round-11 structure (1063.7 us) with init_k transpose section
// rewritten: float4 global loads (was scalar), position-major LDS tf[16][136]
// (pack-phase reads contiguous -> b128, write conflicts 2-way/free).
// Everything else identical.
// ---------------------------------------------------------------------------

constexpr int kB   = 16;
constexpr int kCin = 768;
constexpr int kHW  = 400;
constexpr int kWpx = 20;
constexpr int kHpx = 20;
constexpr int kD   = 512;
constexpr int kLen = 800;
constexpr int kDff = 1024;
constexpr int kNL  = 6;
constexpr float kEps = 1e-5f;

typedef __attribute__((ext_vector_type(8))) short s8v;
typedef __attribute__((ext_vector_type(4))) short s4v;
typedef __attribute__((ext_vector_type(4))) float f4v;

__device__ __forceinline__ int swzk(int row, int k) {
  return (k & ~31) | ((((k >> 3) + (row >> 1)) & 3) << 3) | (k & 7);
}

__device__ __forceinline__ unsigned short f2b(float f) {
  union { __hip_bfloat16 h; unsigned short u; } cv;
  cv.h = __float2bfloat16(f);
  return cv.u;
}

__device__ __forceinline__ float b2f(unsigned short u) {
  return __uint_as_float(((unsigned)u) << 16);
}

__device__ __forceinline__ void gll(const unsigned short* g, unsigned short* l) {
  __builtin_amdgcn_global_load_lds(
      (const __attribute__((address_space(1))) unsigned int*)g,
      (__attribute__((address_space(3))) unsigned int*)l, 16, 0, 0);
}

// ------------------------------ block reduce -------------------------------
__device__ __forceinline__ void breduce2(float& s, float& s2, float* sh) {
#pragma unroll
  for (int o = 32; o > 0; o >>= 1) {
    s  += __shfl_down(s, o);
    s2 += __shfl_down(s2, o);
  }
  const int wid = threadIdx.x >> 6, lane = threadIdx.x & 63;
  if (lane == 0) { sh[wid] = s; sh[4 + wid] = s2; }
  __syncthreads();
  if (threadIdx.x == 0) {
    sh[0] = sh[0] + sh[1] + sh[2] + sh[3];
    sh[4] = sh[4] + sh[5] + sh[6] + sh[7];
  }
  __syncthreads();
  s = sh[0]; s2 = sh[4];
}

// ------------------------------- MFMA GEMM ---------------------------------
// EPI 1: bf16 Cb[row*ldc + swzk] = relu(acc+bias)            (ffn hidden)
// EPI 2: bf16 Cb[row*512+col] = acc+bias + res(srcb swz)     (pre-LN y)
// EPI 3: bf16 Cb[((row/400)*Nreal+col)*400 + row%400] = acc+bias (conv out)
// EPI 4: col<512 -> bf16 Cb[row*512+col] (value, plain);
//        col in [512,704) -> bf16 Cb2[row*192+c] = acc + aux[(row%800)*192+c]
// EPI 5: posWc writer: Cf[((col>>8)*800 + row)*192 + (col&255)] = acc+bias
// EPI 6: plain bf16 Cb[row*512+col]; rows >= 6400 use resb/aux as W/bias
template<int EPI>
__global__ __launch_bounds__(256)
void mgemm(const unsigned short* __restrict__ Abf,
           const unsigned short* __restrict__ Bw,
           const float* __restrict__ bias,
           const unsigned short* __restrict__ resb,
           float* __restrict__ Cf, unsigned short* __restrict__ Cb2,
           const float* __restrict__ aux,
           unsigned short* __restrict__ Cb,
           int K, int ldc, int Nreal)
{
  __shared__ unsigned short As[3][4096];
  __shared__ unsigned short Bs[3][4096];
  const int tid = threadIdx.x;
  const int w = tid >> 6, l = tid & 63;

  // bijective XCD-aware swizzle (m204)
  const int gx = gridDim.x;
  const int nwg = gx * gridDim.y;
  const int bid = blockIdx.y * gx + blockIdx.x;
  const int q = nwg >> 3, r = nwg & 7;
  const int xcd = bid & 7, idx = bid >> 3;
  const int wgid = (xcd < r ? xcd * (q + 1) : r * (q + 1) + (xcd - r) * q) + idx;
  const int m0 = (wgid / gx) * 128;
  const int n0 = (wgid % gx) * 128;

  if (EPI == 6 && m0 >= 6400) { Bw = resb; bias = aux; }

  f4v acc[4][4] = {};

  const int srow = w * 32 + (l >> 2);
  const unsigned short* ga0 = Abf + (size_t)(m0 + srow) * K + (l & 3) * 8;
  const unsigned short* ga1 = ga0 + (size_t)16 * K;
  const unsigned short* gb0 = Bw + (size_t)(n0 + srow) * K + (l & 3) * 8;
  const unsigned short* gb1 = gb0 + (size_t)16 * K;
  const int lb0 = (w * 32) * 32;
  const int lb1 = (w * 32 + 16) * 32;

  int aoff[4], boff[4];
#pragma unroll
  for (int f = 0; f < 4; f++) {
    const int ra = (w >> 1) * 64 + f * 16 + (l & 15);
    aoff[f] = ra * 32 + ((((l >> 4) + (ra >> 1)) & 3) << 3);
    const int rb = (w & 1) * 64 + f * 16 + (l & 15);
    boff[f] = rb * 32 + ((((l >> 4) + (rb >> 1)) & 3) << 3);
  }

#define STAGEG(ko, bi) do { \
    gll(ga0 + (ko), &As[bi][lb0]); gll(ga1 + (ko), &As[bi][lb1]); \
    gll(gb0 + (ko), &Bs[bi][lb0]); gll(gb1 + (ko), &Bs[bi][lb1]); } while (0)

  const int NT = K >> 5;
  STAGEG(0, 0);
  STAGEG(32, 1);

  int cur = 0;
  int bpre = 2;
  int kpre = 64;
  for (int t = 0; t < NT; ++t) {
    if (t + 1 < NT) asm volatile("s_waitcnt vmcnt(4)" ::: "memory");
    else            asm volatile("s_waitcnt vmcnt(0)" ::: "memory");
    __builtin_amdgcn_s_barrier();
    __builtin_amdgcn_sched_barrier(0);
    if (t + 2 < NT) STAGEG(kpre, bpre);
    s8v af[4], bf4[4];
#pragma unroll
    for (int f = 0; f < 4; f++) {
      af[f]  = *(const s8v*)&As[cur][aoff[f]];
      bf4[f] = *(const s8v*)&Bs[cur][boff[f]];
    }
    __builtin_amdgcn_s_setprio(1);
#pragma unroll
    for (int i = 0; i < 4; i++)
#pragma unroll
      for (int j = 0; j < 4; j++)
        acc[i][j] = __builtin_amdgcn_mfma_f32_16x16x32_bf16(af[i], bf4[j], acc[i][j], 0, 0, 0);
    __builtin_amdgcn_s_setprio(0);
    kpre += 32;
    bpre = (bpre == 2) ? 0 : bpre + 1;
    cur  = (cur == 2) ? 0 : cur + 1;
  }
#undef STAGEG

  // C/D layout: col=lane&15, row=(lane>>4)*4+reg
  const int colb = n0 + (w & 1) * 64;
  const int rowb = m0 + (w >> 1) * 64 + (l >> 4) * 4;
#pragma unroll
  for (int i = 0; i < 4; i++) {
#pragma unroll
    for (int j = 0; j < 4; j++) {
      const int col = colb + j * 16 + (l & 15);
      float bv;
      if (EPI == 4) bv = (col < kD) ? bias[col] : 0.0f;
      else          bv = bias[col];
#pragma unroll
      for (int r2 = 0; r2 < 4; r2++) {
        const int row = rowb + i * 16 + r2;
        float v = acc[i][j][r2] + bv;
        if (EPI == 1) {
          Cb[(size_t)row * ldc + swzk(row, col)] = f2b(fmaxf(v, 0.0f));
        } else if (EPI == 2) {
          v += b2f(resb[(size_t)row * kD + swzk(row, col)]);
          Cb[(size_t)row * kD + col] = f2b(v);
        } else if (EPI == 3) {
          const int bb = row / kHW, p = row % kHW;
          Cb[((size_t)bb * Nreal + col) * kHW + p] = f2b(v);
        } else if (EPI == 4) {
          if (col < kD) {
            Cb[(size_t)row * kD + col] = f2b(v);
          } else {
            const int c = col - kD;
            if (c < 192)
              Cb2[(size_t)row * 192 + c] = f2b(v + aux[(size_t)(row % kLen) * 192 + c]);
          }
        } else if (EPI == 5) {
          if (row < kLen) {
            const int ll = col >> 8, c = col & 255;
            if (c < 192)
              Cf[(((size_t)ll * kLen) + row) * 192 + c] = v;
          }
        } else {  // EPI == 6
          Cb[(size_t)row * kD + col] = f2b(v);
        }
      }
    }
  }
}

// -------------------------- weight conversions -----------------------------
__device__ __forceinline__ void cvt8t(const float* __restrict__ W,
                                      unsigned short* __restrict__ out,
                                      int K, int N, int g)
{
  const int n = g % N;
  const int k = (g / N) * 8;
  s8v p;
#pragma unroll
  for (int j = 0; j < 8; j++) p[j] = (short)f2b(W[(size_t)(k + j) * N + n]);
  const int base = n * K + (k & ~31) + ((((k >> 3) + (n >> 1)) & 3) << 3);
  *(s8v*)&out[base] = p;
}

// ---------------------- ALL init work, one dispatch -------------------------
// sections (blockIdx ranges):
//   [0, 4800)        input transpose: 128ch x 16pos tiles (float4 loads,
//                    pos-major LDS, contiguous pack reads, s8v swz writes)
//   [4800, 5184)     both input conv weights -> wcs
//   [5184, 5798)     posfb + woaw_all + biasall  (pre)
//   [5798, 10790)    all 6 layers' weights -> wall (832 blocks/layer)
__global__ __launch_bounds__(256)
void init_k(const float* __restrict__ inv, const float* __restrict__ ini,
            const float* __restrict__ W0, const float* __restrict__ W1,
            const float* __restrict__ level_embed,
            const float* __restrict__ off_w, const float* __restrict__ aw_w,
            const float* __restrict__ off_b, const float* __restrict__ aw_b,
            const float* __restrict__ vp_w, const float* __restrict__ op_w,
            const float* __restrict__ f1w_a, const float* __restrict__ f2w_a,
            unsigned short* __restrict__ tin_out, unsigned short* __restrict__ wcs,
            unsigned short* __restrict__ posfb, unsigned short* __restrict__ woaw_all,
            float* __restrict__ biasall, unsigned short* __restrict__ wall)
{
  __shared__ float tf[16][136];
  int bid = blockIdx.x;

  if (bid < 4800) {                     // ---- input transpose ----
    const int z = bid / 150;            // mod*16+b
    const int rem = bid % 150;
    const int c0 = (rem / 25) * 128;
    const int p0 = (rem % 25) * 16;
    const int mod = z >> 4, b = z & 15;
    const float* in = (mod ? ini : inv) + (size_t)b * kCin * kHW;
#pragma unroll
    for (int it = 0; it < 2; it++) {
      const int slot = it * 256 + threadIdx.x;   // < 512
      const int c = slot >> 2;                    // channel 0..127
      const int q = slot & 3;                     // position quad
      const float4 v = *(const float4*)(in + (size_t)(c0 + c) * kHW + p0 + q * 4);
      tf[q * 4 + 0][c] = v.x;
      tf[q * 4 + 1][c] = v.y;
      tf[q * 4 + 2][c] = v.z;
      tf[q * 4 + 3][c] = v.w;
    }
    __syncthreads();
    const int p   = threadIdx.x >> 4;
    const int oct = threadIdx.x & 15;
    const int row = z * kHW + p0 + p;
    const int c   = c0 + oct * 8;
    s8v o;
#pragma unroll
    for (int cc = 0; cc < 8; cc++) o[cc] = (short)f2b(tf[p][oct * 8 + cc]);
    *(s8v*)&tin_out[(size_t)row * kCin + swzk(row, c)] = o;
    return;
  }
  bid -= 4800;

  if (bid < 384) {                      // ---- conv weights (av, ai) ----
    int gid = bid * 256 + threadIdx.x;  // < 2*512*96
    const float* W = W0;
    unsigned short* o = wcs;
    if (gid >= 49152) { gid -= 49152; W = W1; o = wcs + 393216; }
    const int n = gid / 96;
    const int k = (gid % 96) * 8;
    s8v p;
#pragma unroll
    for (int j = 0; j < 8; j++) p[j] = (short)f2b(W[(size_t)n * kCin + k + j]);
    const int base = n * kCin + (k & ~31) + ((((k >> 3) + (n >> 1)) & 3) << 3);
    *(s8v*)&o[base] = p;
    return;
  }
  bid -= 384;

  if (bid < 614) {                      // ---- pre: posfb + woaw + biases ----
    int g = bid * 256 + threadIdx.x;
    if (g < 57344) {                    // posfb: 896*64
      const int d0 = (g & 63) * 8;
      const int tt2 = g >> 6;
      s8v o;
      if (tt2 >= kLen) {
#pragma unroll
        for (int j = 0; j < 8; j++) o[j] = 0;
      } else {
        const int lvl = tt2 / kHW;
        const int tt = tt2 % kHW;
        const int yy = tt / kWpx, xx = tt % kWpx;
#pragma unroll
        for (int j = 0; j < 8; j++) {
          const int d = d0 + j;
          const int dd = d & 255;
          const float e = (d < 256) ? ((float)(yy + 1) * (6.283185307179586f / kHpx))
                                    : ((float)(xx + 1) * (6.283185307179586f / kWpx));
          const float dimt = powf(10000.0f, (float)(dd >> 1) / 128.0f);
          const float pp = e / dimt;
          const float val = (dd & 1) ? cosf(pp) : sinf(pp);
          o[j] = (short)f2b(val + level_embed[lvl * kD + d]);
        }
      }
      *(s8v*)&posfb[(size_t)tt2 * kD + swzk(tt2, d0)] = o;
      return;
    }
    g -= 57344;
    if (g < 98304) {                    // woaw_all
      const int l = g >> 14;
      const int gg = g & 16383;
      const int n = gg & 255;
      const int k = (gg >> 8) * 8;
      const float* ow = off_w + (size_t)l * kD * 128;
      const float* aww = aw_w + (size_t)l * kD * 64;
      s8v p;
#pragma unroll
      for (int j = 0; j < 8; j++) {
        float v = 0.0f;
        if (n < 128)      v = ow[(size_t)(k + j) * 128 + n];
        else if (n < 192) v = aww[(size_t)(k + j) * 64 + (n - 128)];
        p[j] = (short)f2b(v);
      }
      const int row = l * 256 + n;
      const int base = row * 512 + (k & ~31) + ((((k >> 3) + (row >> 1)) & 3) << 3);
      *(s8v*)&woaw_all[base] = p;
      return;
    }
    g -= 98304;                         // biasall < 1536
    if (g < 1536) {
      const int l = g >> 8, c = g & 255;
      float v = 0.0f;
      if (c < 128)      v = off_b[l * 128 + c];
      else if (c < 192) v = aw_b[l * 64 + (c - 128)];
      biasall[l * 256 + c] = v;
    }
    return;
  }
  bid -= 614;

  {                                     // ---- all layer weights -> wall ----
    const int lyr = bid / 832;
    int g = (bid % 832) * 256 + threadIdx.x;
    unsigned short* wl = wall + (size_t)lyr * 1703936;
    if (g < 32768) { cvt8t(vp_w + (size_t)lyr * kD * kD, wl, 512, 512, g); return; }
    g -= 32768;
    if (g < 16384) {                    // [ow|aww] -> wcomb rows 512..767
      const int n = g & 255;
      const int k = (g >> 8) * 8;
      const float* ow  = off_w + (size_t)lyr * kD * 128;
      const float* aww = aw_w  + (size_t)lyr * kD * 64;
      s8v p;
#pragma unroll
      for (int j = 0; j < 8; j++) {
        float v = 0.0f;
        if (n < 128)      v = ow[(size_t)(k + j) * 128 + n];
        else if (n < 192) v = aww[(size_t)(k + j) * 64 + (n - 128)];
        p[j] = (short)f2b(v);
      }
      const int row = 512 + n;
      const int base = row * 512 + (k & ~31) + ((((k >> 3) + (row >> 1)) & 3) << 3);
      *(s8v*)&wl[base] = p;
      return;
    }
    g -= 16384;
    if (g < 32768) { cvt8t(op_w + (size_t)lyr * kD * kD, wl + 393216, 512, 512, g); return; }
    g -= 32768;
    if (g < 65536) { cvt8t(f1w_a + (size_t)lyr * kD * kDff, wl + 655360, 512, 1024, g); return; }
    g -= 65536;
    cvt8t(f2w_a + (size_t)lyr * kDff * kD, wl + 1179648, 1024, 512, g);
  }
}

// ------------------ GroupNorm (token-major, bf16 input) ---------------------
__global__ __launch_bounds__(256)
void gn_stats_tok_k(const unsigned short* __restrict__ x, float* __restrict__ stats)
{
  __shared__ float sh[8];
  const int mb = blockIdx.x >> 5;   // mod*16+b
  const int g = blockIdx.x & 31;
  const unsigned short* xb = x + (size_t)mb * kHW * kD + g * 16;
  float s = 0.f, s2 = 0.f;
  for (int i = threadIdx.x; i < 800; i += 256) {
    const int p = i >> 1, half = i & 1;
    const s8v u = *(const s8v*)&xb[(size_t)p * kD + half * 8];
#pragma unroll
    for (int j = 0; j < 8; j++) {
      const float v = b2f((unsigned short)u[j]);
      s += v; s2 += v * v;
    }
  }
  breduce2(s, s2, sh);
  if (threadIdx.x == 0) {
    const float mean = s / (kHW * 16.0f);
    const float var  = s2 / (kHW * 16.0f) - mean * mean;
    stats[blockIdx.x * 2]     = mean;
    stats[blockIdx.x * 2 + 1] = rsqrtf(var + kEps);
  }
}

__global__ void gn_norm_tok_k(const unsigned short* __restrict__ x,
                              unsigned short* __restrict__ srcb,
                              const float* __restrict__ stats,
                              const float* __restrict__ gv, const float* __restrict__ bev,
                              const float* __restrict__ gi, const float* __restrict__ bei)
{
  const int gid = blockIdx.x * 256 + threadIdx.x;   // < 12800*64
  const int d0 = (gid & 63) * 8;
  const int rl = gid >> 6;                          // (mod*16+b)*400+p
  const int mb = rl / kHW;
  const int p  = rl - mb * kHW;
  const int mod = mb >> 4, b = mb & 15;
  const int g = d0 >> 4;
  const float mean = stats[(mb * 32 + g) * 2];
  const float rstd = stats[(mb * 32 + g) * 2 + 1];
  const float* gam = mod ? gi : gv;
  const float* bet = mod ? bei : bev;
  const s8v u = *(const s8v*)&x[(size_t)rl * kD + d0];
  const int row = b * kLen + mod * kHW + p;
  s8v o;
#pragma unroll
  for (int j = 0; j < 8; j++)
    o[j] = (short)f2b((b2f((unsigned short)u[j]) - mean) * rstd * gam[d0 + j] + bet[d0 + j]);
  *(s8v*)&srcb[(size_t)row * kD + swzk(row, d0)] = o;
}

// ---------------- GroupNorm (chan-major, bf16 scratch input) ----------------
__global__ __launch_bounds__(256)
void gn_stats_ch_k(const unsigned short* __restrict__ x, float* __restrict__ stats)
{
  __shared__ float sh[8];
  const int b = blockIdx.x >> 5;
  const int g = blockIdx.x & 31;
  const unsigned short* xb = x + (size_t)b * kCin * kHW + (size_t)g * 24 * kHW;
  float s = 0.f, s2 = 0.f;
  for (int i = threadIdx.x; i < 1200; i += 256) {
    const s8v u = *(const s8v*)&xb[(size_t)i * 8];
#pragma unroll
    for (int j = 0; j < 8; j++) {
      const float v = b2f((unsigned short)u[j]);
      s += v; s2 += v * v;
    }
  }
  breduce2(s, s2, sh);
  if (threadIdx.x == 0) {
    const float mean = s / (24.0f * kHW);
    const float var  = s2 / (24.0f * kHW) - mean * mean;
    stats[blockIdx.x * 2]     = mean;
    stats[blockIdx.x * 2 + 1] = rsqrtf(var + kEps);
  }
}

__global__ void gn_norm_ch_k(const unsigned short* __restrict__ x, float* __restrict__ out,
                             const float* __restrict__ stats,
                             const float* __restrict__ gam, const float* __restrict__ bet)
{
  const int gid = blockIdx.x * 256 + threadIdx.x;   // < 16*768*400/8
  const int idx8 = gid * 8;
  const int rest = idx8 / kHW;
  const int c = rest % kCin;
  const int b = rest / kCin;
  const int g = c / 24;
  const float mean = stats[(b * 32 + g) * 2];
  const float rstd = stats[(b * 32 + g) * 2 + 1];
  const float gg = gam[c], bb = bet[c];
  const s8v u = *(const s8v*)&x[idx8];
  float4 o0, o1;
  o0.x = (b2f((unsigned short)u[0]) - mean) * rstd * gg + bb;
  o0.y = (b2f((unsigned short)u[1]) - mean) * rstd * gg + bb;
  o0.z = (b2f((unsigned short)u[2]) - mean) * rstd * gg + bb;
  o0.w = (b2f((unsigned short)u[3]) - mean) * rstd * gg + bb;
  o1.x = (b2f((unsigned short)u[4]) - mean) * rstd * gg + bb;
  o1.y = (b2f((unsigned short)u[5]) - mean) * rstd * gg + bb;
  o1.z = (b2f((unsigned short)u[6]) - mean) * rstd * gg + bb;
  o1.w = (b2f((unsigned short)u[7]) - mean) * rstd * gg + bb;
  *(float4*)(out + idx8)     = o0;
  *(float4*)(out + idx8 + 4) = o1;
}

// ------------- modality-specific LayerNorm (wave/row, bf16 in) --------------
__global__ __launch_bounds__(256)
void ln4_k(const unsigned short* __restrict__ x, unsigned short* __restrict__ outb,
           const float* __restrict__ gamma, const float* __restrict__ beta)
{
  const int row = blockIdx.x * 4 + (threadIdx.x >> 6);
  const int l = threadIdx.x & 63;
  const int mod = ((row % kLen) < kHW) ? 0 : 1;
  const s8v u = *(const s8v*)&x[(size_t)row * kD + l * 8];
  float v[8];
#pragma unroll
  for (int j = 0; j < 8; j++) v[j] = b2f((unsigned short)u[j]);
  float s = 0.f, s2 = 0.f;
#pragma unroll
  for (int j = 0; j < 8; j++) { s += v[j]; s2 += v[j] * v[j]; }
#pragma unroll
  for (int o = 32; o > 0; o >>= 1) {
    s  += __shfl_xor(s, o);
    s2 += __shfl_xor(s2, o);
  }
  const float mean = s * (1.0f / kD);
  const float var  = s2 * (1.0f / kD) - mean * mean;
  const float rstd = rsqrtf(var + kEps);
  const float* g  = gamma + mod * kD + l * 8;
  const float* be = beta  + mod * kD + l * 8;
  s8v o8;
#pragma unroll
  for (int j = 0; j < 8; j++)
    o8[j] = (short)f2b((v[j] - mean) * rstd * g[j] + be[j]);
  *(s8v*)&outb[(size_t)row * kD + swzk(row, l * 8)] = o8;
}

// ------------------- deformable sampling (bf16 value/offaw) -----------------
__global__ __launch_bounds__(256)
void sample_k(const unsigned short* __restrict__ value,
              const unsigned short* __restrict__ offaw,
              unsigned short* __restrict__ out)
{
  __shared__ float wls[2][64][8];   // [tok][combo][w0,i0,...,w3,i3]
  const int tid = threadIdx.x;
  const int tok = tid >> 7;
  const int wt  = tid & 127;
  const int token = blockIdx.x * 2 + tok;       // < 12800
  const int b = token / kLen;
  const int t = token % kLen;
  const int tt = t % kHW;

  if (wt < 64) {
    const int h = wt >> 3, lp = wt & 7, lvl = lp >> 2, p = lp & 3;
    const unsigned short* oa = offaw + (size_t)token * 192;
    const float lg = b2f(oa[128 + h * 8 + lp]);
    float mx = lg;
#pragma unroll
    for (int msk = 1; msk < 8; msk <<= 1) mx = fmaxf(mx, __shfl_xor(mx, msk));
    const float ex = __expf(lg - mx);
    float ssum = ex;
#pragma unroll
    for (int msk = 1; msk < 8; msk <<= 1) ssum += __shfl_xor(ssum, msk);
    const float aw = ex / ssum;

    const float x = (float)(tt % kWpx) + b2f(oa[h * 16 + lvl * 8 + p * 2]);
    const float y = (float)(tt / kWpx) + b2f(oa[h * 16 + lvl * 8 + p * 2 + 1]);
    const float x0f = floorf(x), y0f = floorf(y);
    const float wx = x - x0f, wy = y - y0f;
    const int x0 = (int)x0f, y0 = (int)y0f;
    const int rowbase = b * kLen + lvl * kHW;
#pragma unroll
    for (int dy = 0; dy < 2; dy++) {
#pragma unroll
      for (int dx = 0; dx < 2; dx++) {
        const int ix = x0 + dx, iy = y0 + dy;
        const bool valid = (ix >= 0) & (ix < kWpx) & (iy >= 0) & (iy < kHpx);
        const float cw = (dx ? wx : 1.0f - wx) * (dy ? wy : 1.0f - wy);
        const float w = valid ? aw * cw : 0.0f;
        const int ixc = min(max(ix, 0), kWpx - 1);
        const int iyc = min(max(iy, 0), kHpx - 1);
        const int r = rowbase + iyc * kWpx + ixc;
        const int cn = dy * 2 + dx;
        wls[tok][wt][cn * 2]     = w;
        wls[tok][wt][cn * 2 + 1] = __int_as_float(r);
      }
    }
  }
  __syncthreads();

  const int c0 = wt * 4;
  const int h = wt >> 4;
  float acc0 = 0.f, acc1 = 0.f, acc2 = 0.f, acc3 = 0.f;
  const unsigned short* vb = value + c0;
#pragma unroll
  for (int pp = 0; pp < 8; pp++) {
    const float* wl = wls[tok][h * 8 + pp];
#pragma unroll
    for (int cn = 0; cn < 4; cn++) {
      const float w = wl[cn * 2];
      const int r = __float_as_int(wl[cn * 2 + 1]);
      const s4v q = *(const s4v*)(vb + (size_t)r * kD);
      acc0 += w * b2f((unsigned short)q[0]);
      acc1 += w * b2f((unsigned short)q[1]);
      acc2 += w * b2f((unsigned short)q[2]);
      acc3 += w * b2f((unsigned short)q[3]);
    }
  }
  const int sk = swzk(token, c0);
  s4v o;
  o[0] = (short)f2b(acc0); o[1] = (short)f2b(acc1);
  o[2] = (short)f2b(acc2); o[3] = (short)f2b(acc3);
  *(s4v*)&out[(size_t)token * kD + sk] = o;
}

// -------- token-sum (srcb halves -> tokb swz) + as_w convert, fused ---------
__global__ void sumcvt_k(const unsigned short* __restrict__ srcb,
                         unsigned short* __restrict__ tokb,
                         const float* __restrict__ asw,
                         unsigned short* __restrict__ wcs)
{
  const int bid = blockIdx.x;
  if (bid < 1600) {                              // sumtok: 16*400*64 items
    const int gid = bid * 256 + threadIdx.x;
    const int d0 = (gid & 63) * 8;
    const int rest = gid >> 6;
    const int b = rest / kHW, p = rest % kHW;
    const int r1 = b * kLen + p;
    const int r2 = r1 + kHW;
    const int ro = b * kHW + p;
    const s8v u1 = *(const s8v*)&srcb[(size_t)r1 * kD + swzk(r1, d0)];
    const s8v u2 = *(const s8v*)&srcb[(size_t)r2 * kD + swzk(r2, d0)];
    s8v o;
#pragma unroll
    for (int j = 0; j < 8; j++)
      o[j] = (short)f2b(b2f((unsigned short)u1[j]) + b2f((unsigned short)u2[j]));
    *(s8v*)&tokb[(size_t)ro * kD + swzk(ro, d0)] = o;
    return;
  }
  const int gid = (bid - 1600) * 256 + threadIdx.x;   // < 768*64 (N=768, K=512)
  const int n = gid / 64;
  const int k = (gid % 64) * 8;
  s8v p;
#pragma unroll
  for (int j = 0; j < 8; j++) p[j] = (short)f2b(asw[(size_t)n * kD + k + j]);
  const int base = n * kD + (k & ~31) + ((((k >> 3) + (n >> 1)) & 3) << 3);
  *(s8v*)&wcs[base] = p;
}

// ------------------------------- launcher -----------------------------------
extern "C" void kernel_launch(void* const* d_in, const int* in_sizes, int n_in,
                              void* d_out, int out_size, void* d_ws, size_t ws_size,
                              hipStream_t stream)
{
  const float* input_v     = (const float*)d_in[0];
  const float* input_i     = (const float*)d_in[1];
  const float* av_w        = (const float*)d_in[2];
  const float* av_b        = (const float*)d_in[3];
  const float* av_g        = (const float*)d_in[4];
  const float* av_be       = (const float*)d_in[5];
  const float* ai_w        = (const float*)d_in[6];
  const float* ai_b        = (const float*)d_in[7];
  const float* ai_g        = (const float*)d_in[8];
  const float* ai_be       = (const float*)d_in[9];
  const float* level_embed = (const float*)d_in[10];
  const float* off_w       = (const float*)d_in[11];
  const float* off_b       = (const float*)d_in[12];
  const float* aw_w        = (const float*)d_in[13];
  const float* aw_b        = (const float*)d_in[14];
  const float* vp_w        = (const float*)d_in[15];
  const float* vp_b        = (const float*)d_in[16];
  const float* op_w        = (const float*)d_in[17];
  const float* op_b        = (const float*)d_in[18];
  const float* ln1_g       = (const float*)d_in[19];
  const float* ln1_b       = (const float*)d_in[20];
  const float* ffn1_w      = (const float*)d_in[21];
  const float* ffn1_b      = (const float*)d_in[22];
  const float* ffn2_w      = (const float*)d_in[23];
  const float* ffn2_b      = (const float*)d_in[24];
  const float* ln2_g       = (const float*)d_in[25];
  const float* ln2_b       = (const float*)d_in[26];
  const float* as_w        = (const float*)d_in[27];
  const float* as_b        = (const float*)d_in[28];
  const float* as_g        = (const float*)d_in[29];
  const float* as_be       = (const float*)d_in[30];

  // ------- workspace layout -------
  unsigned short* offawb = (unsigned short*)d_ws;               // 2,457,600 sh
  float* posWc   = (float*)(offawb + 2457600);                  //   921,600 f
  float* biasall = posWc   + (size_t)921600;                    //     1,536 f
  float* stats   = biasall + (size_t)1536;                      //     2,048 f
  unsigned short* srcb     = (unsigned short*)(stats + 2048);   //  6,553,600 sh
  unsigned short* bufA     = srcb     + (size_t)6553600;        // 13,107,200 sh
  unsigned short* bufB     = bufA     + (size_t)13107200;       //  6,553,600 sh
  unsigned short* wall     = bufB     + (size_t)6553600;        // 10,223,616 sh
  unsigned short* wcs      = wall     + (size_t)10223616;       //    786,432 sh
  unsigned short* woaw_all = wcs      + (size_t)786432;         //    786,432 sh
  unsigned short* posfb    = woaw_all + (size_t)786432;         //    458,752 sh
  unsigned short* wallb = wall;   // bf16 conv scratch (aliases weight arena)

  const int M = kB * kLen;   // 12800

  // ---- ALL init work (transpose, weight cvts, pos feats) in one dispatch ----
  init_k<<<dim3(10790), 256, 0, stream>>>(
      input_v, input_i, av_w, ai_w, level_embed, off_w, aw_w, off_b, aw_b,
      vp_w, op_w, ffn1_w, ffn2_w,
      bufA, wcs, posfb, woaw_all, biasall, wall);

  // posWc = posf @ [ow|aww] + bias
  mgemm<5><<<dim3(12, 7), 256, 0, stream>>>(
      posfb, woaw_all, biasall, nullptr, posWc, nullptr, nullptr, nullptr,
      512, 0, 0);

  // ---- input convs (both modalities, one GEMM) + GN -> srcb ----
  mgemm<6><<<dim3(4, 100), 256, 0, stream>>>(
      bufA, wcs, av_b, wcs + 393216, nullptr, nullptr, ai_b, bufB, 768, 512, 0);
  gn_stats_tok_k<<<dim3(1024), 256, 0, stream>>>(bufB, stats);
  gn_norm_tok_k<<<dim3(3200), 256, 0, stream>>>(
      bufB, srcb, stats, av_g, av_be, ai_g, ai_be);

  for (int l = 0; l < kNL; l++) {
    unsigned short* wcomb = wall + (size_t)l * 1703936;
    unsigned short* wop   = wcomb + 393216;
    unsigned short* wf1   = wcomb + 655360;
    unsigned short* wf2   = wcomb + 1179648;
    const float* vbl  = vp_b   + (size_t)l * kD;
    const float* opbl = op_b   + (size_t)l * kD;
    const float* l1g  = ln1_g  + (size_t)l * 2 * kD;
    const float* l1b  = ln1_b  + (size_t)l * 2 * kD;
    const float* f1b  = ffn1_b + (size_t)l * kDff;
    const float* f2b_ = ffn2_b + (size_t)l * kD;
    const float* l2g  = ln2_g  + (size_t)l * 2 * kD;
    const float* l2b  = ln2_b  + (size_t)l * 2 * kD;

    // fused: value bf16 (bufA) | offaw bf16 (+posWc)
    mgemm<4><<<dim3(6, 100), 256, 0, stream>>>(
        srcb, wcomb, vbl, nullptr, nullptr, offawb, posWc + (size_t)l * 153600,
        bufA, 512, 0, 0);

    // sampling -> bufB (bf16 swz)
    sample_k<<<dim3(M / 2), 256, 0, stream>>>(bufA, offawb, bufB);

    // y = srcb + sampled @ op + opb -> bufA (bf16 plain)
    mgemm<2><<<dim3(4, 100), 256, 0, stream>>>(
        bufB, wop, opbl, srcb, nullptr, nullptr, nullptr, bufA, 512, 512, 0);

    // srcb = LN_spec(y)
    ln4_k<<<dim3(M / 4), 256, 0, stream>>>(bufA, srcb, l1g, l1b);

    // FFN full-M: hidden -> bufA (swz, relu); y -> bufB (plain)
    mgemm<1><<<dim3(8, 100), 256, 0, stream>>>(
        srcb, wf1, f1b, nullptr, nullptr, nullptr, nullptr, bufA, 512, 1024, 0);
    mgemm<2><<<dim3(4, 100), 256, 0, stream>>>(
        bufA, wf2, f2b_, srcb, nullptr, nullptr, nullptr, bufB, 1024, 512, 0);

    // srcb = LN_spec(y)
    ln4_k<<<dim3(M / 4), 256, 0, stream>>>(bufB, srcb, l2g, l2b);
  }

  // ---- out = GN(conv1x1(src_v + src_i)); bf16 scratch in wallb ----
  sumcvt_k<<<dim3(1792), 256, 0, stream>>>(srcb, bufA, as_w, wcs);
  mgemm<3><<<dim3(6, 50), 256, 0, stream>>>(
      bufA, wcs, as_b, nullptr, nullptr, nullptr, nullptr, wallb, 512, 0, 768);
  gn_stats_ch_k<<<dim3(kB * 32), 256, 0, stream>>>(wallb, stats);
  gn_norm_ch_k<<<dim3(2400), 256, 0, stream>>>(
      wallb, (float*)d_out, stats, as_g, as_be);
}